// Round 1
// baseline (411.390 us; speedup 1.0000x reference)
//
#include <hip/hip_runtime.h>
#include <hip/hip_bf16.h>
#include <hip/hip_fp16.h>

#define B_ 8
#define S_ 2048
#define D_ 512
#define H_ 8
#define L_ 5
#define DK_ 64
#define SP_ 2044
#define SPAD_ 2048

typedef _Float16 f16_t;
typedef _Float16 f16x8 __attribute__((ext_vector_type(8)));
typedef float f32x4 __attribute__((ext_vector_type(4)));

static __device__ __forceinline__ f32x4 mfma16(f16x8 a, f16x8 b, f32x4 c) {
    return __builtin_amdgcn_mfma_f32_16x16x32_f16(a, b, c, 0, 0, 0);
}

// ---------------------------------------------------------------------------
// Kernel 1: W0/Wout f32 -> fp16, stored TRANSPOSED: WT[n*512+k] = W[k*512+n]
// ---------------------------------------------------------------------------
__global__ __launch_bounds__(256) void k_convert_w(
    const float* __restrict__ W0, const float* __restrict__ Wout,
    f16_t* __restrict__ WT0, f16_t* __restrict__ WT1) {
    int idx = blockIdx.x * 256 + threadIdx.x;          // 0 .. 2*512*512-1
    int which = idx >> 18;
    int e = idx & 0x3FFFF;
    int k = e >> 9, n = e & 511;
    const float* W = which ? Wout : W0;
    f16_t* WT = which ? WT1 : WT0;
    WT[n * 512 + k] = (f16_t)W[k * 512 + n];
}

// ---------------------------------------------------------------------------
// Kernel 2: q/k local aggregation. One wave per (b,t). f32 math, fp16 store
// into head layout [B][H][SPAD][DK]. q pre-scaled by 1/sqrt(DK)=0.125.
// ---------------------------------------------------------------------------
__global__ __launch_bounds__(256) void k_prep(
    const float* __restrict__ Qin, const float* __restrict__ Kin,
    f16_t* __restrict__ qh, f16_t* __restrict__ kh) {
    const int lane = threadIdx.x & 63;
    const int wid = threadIdx.x >> 6;
    const int gw = blockIdx.x * 4 + wid;               // 0..16383
    const int b = gw >> 11;
    const int t = gw & 2047;
    const float* qb = Qin + (size_t)b * S_ * D_;
    const float* kb = Kin + (size_t)b * S_ * D_;
    const int d0 = lane * 8;

    float qs[8];
    float kl[5][8];
#pragma unroll
    for (int e = 0; e < 8; e++) qs[e] = 0.f;
#pragma unroll
    for (int l = 0; l < L_; l++) {
        int row = t + l; row = row < 2047 ? row : 2047;   // clamp (only pads)
        const float4* qp = (const float4*)(qb + (size_t)row * D_ + d0);
        float4 a = qp[0], c = qp[1];
        qs[0] += a.x; qs[1] += a.y; qs[2] += a.z; qs[3] += a.w;
        qs[4] += c.x; qs[5] += c.y; qs[6] += c.z; qs[7] += c.w;
        const float4* kp = (const float4*)(kb + (size_t)row * D_ + d0);
        float4 ka = kp[0], kc = kp[1];
        kl[l][0] = ka.x; kl[l][1] = ka.y; kl[l][2] = ka.z; kl[l][3] = ka.w;
        kl[l][4] = kc.x; kl[l][5] = kc.y; kl[l][6] = kc.z; kl[l][7] = kc.w;
    }
    float dot[5];
#pragma unroll
    for (int l = 0; l < 5; l++) {
        float d = 0.f;
#pragma unroll
        for (int e = 0; e < 8; e++) d += kl[4][e] * kl[l][e];
        dot[l] = d;
    }
#pragma unroll
    for (int m = 32; m; m >>= 1) {
#pragma unroll
        for (int l = 0; l < 5; l++) dot[l] += __shfl_xor(dot[l], m, 64);
    }
    const float sc = 0.044194173824159216f;            // 1/sqrt(512)
    float mx = dot[0];
#pragma unroll
    for (int l = 1; l < 5; l++) mx = fmaxf(mx, dot[l]);
    float w[5], sum = 0.f;
#pragma unroll
    for (int l = 0; l < 5; l++) { w[l] = __expf((dot[l] - mx) * sc); sum += w[l]; }
    float inv = 1.f / sum;
    float ks[8];
#pragma unroll
    for (int e = 0; e < 8; e++) {
        float v = 0.f;
#pragma unroll
        for (int l = 0; l < 5; l++) v += w[l] * kl[l][e];
        ks[e] = v * inv;
    }
    const int h = d0 >> 6, dk = d0 & 63;
    const size_t ob = ((size_t)(b * H_ + h) * SPAD_ + t) * DK_ + dk;
    f16x8 qpk, kpk;
#pragma unroll
    for (int e = 0; e < 8; e++) {
        qpk[e] = (f16_t)(qs[e] * 0.125f);              // pre-scale 1/sqrt(DK)
        kpk[e] = (f16_t)ks[e];
    }
    *(f16x8*)(qh + ob) = qpk;
    *(f16x8*)(kh + ob) = kpk;
}

// ---------------------------------------------------------------------------
// Kernel 3: GEMM  C[16384][512] = A[16384][512] * W[512][512] + bias
// MODE 0: A = value (f32, row t+4 clamped), C -> vh fp16 head layout
// MODE 1: A = xatt (fp16), C -> d_out f32, rows t<2044 only
// Tile 128x64, 4 waves, BK=32, mfma_f32_16x16x32_f16.
// ---------------------------------------------------------------------------
template <int MODE>
__global__ __launch_bounds__(256) void k_gemm(
    const void* __restrict__ Aptr, const f16_t* __restrict__ WT,
    const float* __restrict__ bias, void* __restrict__ Cptr) {
    __shared__ alignas(16) f16_t Asm[128][40];   // +8 pad (80B stride)
    __shared__ alignas(16) f16_t Bsm[64][40];    // WT tile, [n][k]
    const int tid = threadIdx.x, lane = tid & 63, wid = tid >> 6;
    const int mt = blockIdx.x >> 3, nt = blockIdx.x & 7;
    const int m0 = mt * 128, n0 = nt * 64;
    const int l15 = lane & 15, lg = lane >> 4;
    f32x4 acc[2][4] = {};

    for (int k0 = 0; k0 < 512; k0 += 32) {
        if (MODE == 0) {
            const float* A = (const float*)Aptr;
            int r = tid >> 1, cb = (tid & 1) * 16;
            int rp = m0 + r, b = rp >> 11, t = rp & 2047;
            int vrow = t + 4; vrow = vrow < 2047 ? vrow : 2047;
            const float4* src = (const float4*)(A + ((size_t)b * 2048 + vrow) * 512 + k0 + cb);
            float4 f0 = src[0], f1 = src[1], f2 = src[2], f3 = src[3];
            f16x8 p0, p1;
            p0[0] = (f16_t)f0.x; p0[1] = (f16_t)f0.y; p0[2] = (f16_t)f0.z; p0[3] = (f16_t)f0.w;
            p0[4] = (f16_t)f1.x; p0[5] = (f16_t)f1.y; p0[6] = (f16_t)f1.z; p0[7] = (f16_t)f1.w;
            p1[0] = (f16_t)f2.x; p1[1] = (f16_t)f2.y; p1[2] = (f16_t)f2.z; p1[3] = (f16_t)f2.w;
            p1[4] = (f16_t)f3.x; p1[5] = (f16_t)f3.y; p1[6] = (f16_t)f3.z; p1[7] = (f16_t)f3.w;
            *(f16x8*)&Asm[r][cb] = p0;
            *(f16x8*)&Asm[r][cb + 8] = p1;
        } else {
            const f16_t* A = (const f16_t*)Aptr;
#pragma unroll
            for (int i = 0; i < 2; i++) {
                int ch = tid + 256 * i, r = ch >> 2, off = (ch & 3) * 8;
                *(uint4*)&Asm[r][off] = *(const uint4*)(A + (size_t)(m0 + r) * 512 + k0 + off);
            }
        }
        {
            int nl = tid >> 2, koff = (tid & 3) * 8;
            *(uint4*)&Bsm[nl][koff] = *(const uint4*)(WT + (size_t)(n0 + nl) * 512 + k0 + koff);
        }
        __syncthreads();
        f16x8 af[2], bfr[4];
#pragma unroll
        for (int i = 0; i < 2; i++) af[i] = *(const f16x8*)&Asm[wid * 32 + i * 16 + l15][lg * 8];
#pragma unroll
        for (int c = 0; c < 4; c++) bfr[c] = *(const f16x8*)&Bsm[c * 16 + l15][lg * 8];
#pragma unroll
        for (int i = 0; i < 2; i++) {
#pragma unroll
            for (int c = 0; c < 4; c++) acc[i][c] = mfma16(af[i], bfr[c], acc[i][c]);
        }
        __syncthreads();
    }
#pragma unroll
    for (int i = 0; i < 2; i++) {
#pragma unroll
        for (int c = 0; c < 4; c++) {
#pragma unroll
            for (int r = 0; r < 4; r++) {
                int row = m0 + wid * 32 + i * 16 + lg * 4 + r;
                int col = n0 + c * 16 + l15;
                float v = acc[i][c][r] + bias[col];
                int b = row >> 11, t = row & 2047;
                if (MODE == 0) {
                    f16_t* vh = (f16_t*)Cptr;
                    vh[((size_t)(b * H_ + (col >> 6)) * SPAD_ + t) * DK_ + (col & 63)] = (f16_t)v;
                } else {
                    if (t < SP_) {
                        float* outp = (float*)Cptr;
                        outp[((size_t)b * SP_ + t) * 512 + col] = v;
                    }
                }
            }
        }
    }
}

// ---------------------------------------------------------------------------
// Kernel 4: flash attention. Block = 4 waves, 64 Q-rows (16/wave), one (b,h).
// K/V tiles of 64 staged in LDS (V transposed). Online softmax per row.
// ---------------------------------------------------------------------------
__global__ __launch_bounds__(256) void k_attn(
    const f16_t* __restrict__ qh, const f16_t* __restrict__ kh,
    const f16_t* __restrict__ vh, f16_t* __restrict__ xatt) {
    __shared__ alignas(16) f16_t Ksm[64][72];        // [s][d], +8 pad
    __shared__ alignas(16) f16_t Vsm[64][72];        // transposed: [d][s]
    __shared__ alignas(16) f16_t Psm[4][16][72];     // per-wave P relayout
    const int tid = threadIdx.x, lane = tid & 63, wid = tid >> 6;
    const int bh = blockIdx.x >> 5, qt = blockIdx.x & 31;
    const f16_t* Q = qh + (size_t)bh * SPAD_ * DK_;
    const f16_t* K = kh + (size_t)bh * SPAD_ * DK_;
    const f16_t* V = vh + (size_t)bh * SPAD_ * DK_;
    const int l15 = lane & 15, lg = lane >> 4;
    const int qrow = qt * 64 + wid * 16;

    f16x8 qf[2];
#pragma unroll
    for (int kf = 0; kf < 2; kf++)
        qf[kf] = *(const f16x8*)(Q + (size_t)(qrow + l15) * DK_ + kf * 32 + lg * 8);

    f32x4 acc[4] = {};
    float mrun[4], lrun[4];
#pragma unroll
    for (int r = 0; r < 4; r++) { mrun[r] = -1e30f; lrun[r] = 0.f; }

    for (int s0 = 0; s0 < SPAD_; s0 += 64) {
        // stage K (row-major) and V (transposed)
#pragma unroll
        for (int i = 0; i < 2; i++) {
            int ch = tid + 256 * i, s = ch >> 3, off = (ch & 7) * 8;
            *(uint4*)&Ksm[s][off] = *(const uint4*)(K + (size_t)(s0 + s) * DK_ + off);
            uint4 vv = *(const uint4*)(V + (size_t)(s0 + s) * DK_ + off);
            const f16_t* vp = (const f16_t*)&vv;
#pragma unroll
            for (int e = 0; e < 8; e++) Vsm[off + e][s] = vp[e];
        }
        __syncthreads();

        // S = Q K^T  (q pre-scaled by 1/8)
        f32x4 Sv[4];
#pragma unroll
        for (int n = 0; n < 4; n++) {
            f16x8 kb0 = *(const f16x8*)&Ksm[n * 16 + l15][lg * 8];
            f16x8 kb1 = *(const f16x8*)&Ksm[n * 16 + l15][32 + lg * 8];
            f32x4 s = {};
            s = mfma16(qf[0], kb0, s);
            s = mfma16(qf[1], kb1, s);
            if (s0 + n * 16 + l15 >= SP_) {
                s[0] = -1e30f; s[1] = -1e30f; s[2] = -1e30f; s[3] = -1e30f;
            }
            Sv[n] = s;
        }
        // online softmax: row r lives on the 16 lanes of group lg, reg r
        float tm[4];
#pragma unroll
        for (int r = 0; r < 4; r++)
            tm[r] = fmaxf(fmaxf(Sv[0][r], Sv[1][r]), fmaxf(Sv[2][r], Sv[3][r]));
#pragma unroll
        for (int r = 0; r < 4; r++) {
#pragma unroll
            for (int m = 1; m < 16; m <<= 1) tm[r] = fmaxf(tm[r], __shfl_xor(tm[r], m, 16));
        }
        float alpha[4];
#pragma unroll
        for (int r = 0; r < 4; r++) {
            float nm = fmaxf(mrun[r], tm[r]);
            alpha[r] = __expf(mrun[r] - nm);
            mrun[r] = nm;
        }
        float rs[4] = {0.f, 0.f, 0.f, 0.f};
#pragma unroll
        for (int n = 0; n < 4; n++) {
#pragma unroll
            for (int r = 0; r < 4; r++) {
                float p = __expf(Sv[n][r] - mrun[r]);
                Sv[n][r] = p;
                rs[r] += p;
            }
        }
#pragma unroll
        for (int r = 0; r < 4; r++) {
#pragma unroll
            for (int m = 1; m < 16; m <<= 1) rs[r] += __shfl_xor(rs[r], m, 16);
            lrun[r] = lrun[r] * alpha[r] + rs[r];
        }
#pragma unroll
        for (int c = 0; c < 4; c++) {
#pragma unroll
            for (int r = 0; r < 4; r++) acc[c][r] *= alpha[r];
        }
        // P -> LDS (C-layout) -> A-frags (same wave; DS pipe is in-order)
#pragma unroll
        for (int n = 0; n < 4; n++) {
#pragma unroll
            for (int r = 0; r < 4; r++)
                Psm[wid][lg * 4 + r][n * 16 + l15] = (f16_t)Sv[n][r];
        }
        f16x8 pa0 = *(const f16x8*)&Psm[wid][l15][lg * 8];
        f16x8 pa1 = *(const f16x8*)&Psm[wid][l15][32 + lg * 8];
#pragma unroll
        for (int c = 0; c < 4; c++) {
            f16x8 vb0 = *(const f16x8*)&Vsm[c * 16 + l15][lg * 8];
            f16x8 vb1 = *(const f16x8*)&Vsm[c * 16 + l15][32 + lg * 8];
            acc[c] = mfma16(pa0, vb0, acc[c]);
            acc[c] = mfma16(pa1, vb1, acc[c]);
        }
        __syncthreads();
    }
    const int b = bh >> 3, h = bh & 7;
#pragma unroll
    for (int c = 0; c < 4; c++) {
#pragma unroll
        for (int r = 0; r < 4; r++) {
            int t = qrow + lg * 4 + r;
            int d = h * 64 + c * 16 + l15;
            xatt[((size_t)b * SPAD_ + t) * D_ + d] = (f16_t)(acc[c][r] / lrun[r]);
        }
    }
}

// ---------------------------------------------------------------------------
extern "C" void kernel_launch(void* const* d_in, const int* in_sizes, int n_in,
                              void* d_out, int out_size, void* d_ws, size_t ws_size,
                              hipStream_t stream) {
    const float* query = (const float*)d_in[0];
    const float* key   = (const float*)d_in[1];
    const float* value = (const float*)d_in[2];
    const float* W0    = (const float*)d_in[3];
    const float* b0    = (const float*)d_in[4];
    const float* Wout  = (const float*)d_in[5];
    const float* bout  = (const float*)d_in[6];
    float* out = (float*)d_out;

    char* w = (char*)d_ws;
    const size_t SZ = (size_t)B_ * H_ * SPAD_ * DK_ * sizeof(f16_t);  // 16 MB
    f16_t* qh   = (f16_t*)w; w += SZ;
    f16_t* kh   = (f16_t*)w; w += SZ;
    f16_t* vh   = (f16_t*)w; w += SZ;
    f16_t* xatt = (f16_t*)w; w += SZ;
    f16_t* WT0  = (f16_t*)w; w += (size_t)512 * 512 * sizeof(f16_t);
    f16_t* WT1  = (f16_t*)w; w += (size_t)512 * 512 * sizeof(f16_t);

    k_convert_w<<<2048, 256, 0, stream>>>(W0, Wout, WT0, WT1);
    k_prep<<<4096, 256, 0, stream>>>(query, key, qh, kh);
    k_gemm<0><<<1024, 256, 0, stream>>>((const void*)value, WT0, b0, (void*)vh);
    k_attn<<<2048, 256, 0, stream>>>(qh, kh, vh, xatt);
    k_gemm<1><<<1024, 256, 0, stream>>>((const void*)xatt, WT1, bout, (void*)out);
}

// Round 2
// 244.744 us; speedup vs baseline: 1.6809x; 1.6809x over previous
//
#include <hip/hip_runtime.h>
#include <hip/hip_bf16.h>
#include <hip/hip_fp16.h>

#define B_ 8
#define S_ 2048
#define D_ 512
#define H_ 8
#define L_ 5
#define DK_ 64
#define SP_ 2044
#define SPAD_ 2048

typedef _Float16 f16_t;
typedef _Float16 f16x4 __attribute__((ext_vector_type(4)));
typedef _Float16 f16x8 __attribute__((ext_vector_type(8)));
typedef float f32x4 __attribute__((ext_vector_type(4)));

static __device__ __forceinline__ f32x4 mfma16(f16x8 a, f16x8 b, f32x4 c) {
    return __builtin_amdgcn_mfma_f32_16x16x32_f16(a, b, c, 0, 0, 0);
}

// ---------------------------------------------------------------------------
// Kernel 1: W0/Wout f32 -> fp16, stored TRANSPOSED: WT[n*512+k] = W[k*512+n]
// ---------------------------------------------------------------------------
__global__ __launch_bounds__(256) void k_convert_w(
    const float* __restrict__ W0, const float* __restrict__ Wout,
    f16_t* __restrict__ WT0, f16_t* __restrict__ WT1) {
    int idx = blockIdx.x * 256 + threadIdx.x;          // 0 .. 2*512*512-1
    int which = idx >> 18;
    int e = idx & 0x3FFFF;
    int k = e >> 9, n = e & 511;
    const float* W = which ? Wout : W0;
    f16_t* WT = which ? WT1 : WT0;
    WT[n * 512 + k] = (f16_t)W[k * 512 + n];
}

// ---------------------------------------------------------------------------
// Kernel 2: q/k local aggregation. One wave per (b,t). f32 math, fp16 store
// into head layout [B][H][SPAD][DK]. q pre-scaled by log2(e)/sqrt(DK).
// ---------------------------------------------------------------------------
__global__ __launch_bounds__(256) void k_prep(
    const float* __restrict__ Qin, const float* __restrict__ Kin,
    f16_t* __restrict__ qh, f16_t* __restrict__ kh) {
    const int lane = threadIdx.x & 63;
    const int wid = threadIdx.x >> 6;
    const int gw = blockIdx.x * 4 + wid;               // 0..16383
    const int b = gw >> 11;
    const int t = gw & 2047;
    const float* qb = Qin + (size_t)b * S_ * D_;
    const float* kb = Kin + (size_t)b * S_ * D_;
    const int d0 = lane * 8;

    float qs[8];
    float kl[5][8];
#pragma unroll
    for (int e = 0; e < 8; e++) qs[e] = 0.f;
#pragma unroll
    for (int l = 0; l < L_; l++) {
        int row = t + l; row = row < 2047 ? row : 2047;   // clamp (only pads)
        const float4* qp = (const float4*)(qb + (size_t)row * D_ + d0);
        float4 a = qp[0], c = qp[1];
        qs[0] += a.x; qs[1] += a.y; qs[2] += a.z; qs[3] += a.w;
        qs[4] += c.x; qs[5] += c.y; qs[6] += c.z; qs[7] += c.w;
        const float4* kp = (const float4*)(kb + (size_t)row * D_ + d0);
        float4 ka = kp[0], kc = kp[1];
        kl[l][0] = ka.x; kl[l][1] = ka.y; kl[l][2] = ka.z; kl[l][3] = ka.w;
        kl[l][4] = kc.x; kl[l][5] = kc.y; kl[l][6] = kc.z; kl[l][7] = kc.w;
    }
    float dot[5];
#pragma unroll
    for (int l = 0; l < 5; l++) {
        float d = 0.f;
#pragma unroll
        for (int e = 0; e < 8; e++) d += kl[4][e] * kl[l][e];
        dot[l] = d;
    }
#pragma unroll
    for (int m = 32; m; m >>= 1) {
#pragma unroll
        for (int l = 0; l < 5; l++) dot[l] += __shfl_xor(dot[l], m, 64);
    }
    const float sc = 0.044194173824159216f;            // 1/sqrt(512)
    float mx = dot[0];
#pragma unroll
    for (int l = 1; l < 5; l++) mx = fmaxf(mx, dot[l]);
    float w[5], sum = 0.f;
#pragma unroll
    for (int l = 0; l < 5; l++) { w[l] = __expf((dot[l] - mx) * sc); sum += w[l]; }
    float inv = 1.f / sum;
    float ks[8];
#pragma unroll
    for (int e = 0; e < 8; e++) {
        float v = 0.f;
#pragma unroll
        for (int l = 0; l < 5; l++) v += w[l] * kl[l][e];
        ks[e] = v * inv;
    }
    const int h = d0 >> 6, dk = d0 & 63;
    const size_t ob = ((size_t)(b * H_ + h) * SPAD_ + t) * DK_ + dk;
    const float qscale = 0.125f * 1.4426950408889634f;   // 1/sqrt(DK) * log2(e)
    f16x8 qpk, kpk;
#pragma unroll
    for (int e = 0; e < 8; e++) {
        qpk[e] = (f16_t)(qs[e] * qscale);
        kpk[e] = (f16_t)ks[e];
    }
    *(f16x8*)(qh + ob) = qpk;
    *(f16x8*)(kh + ob) = kpk;
}

// ---------------------------------------------------------------------------
// Kernel 3: GEMM  C[16384][512] = A[16384][512] * W[512][512] + bias
// MODE 0: A = value (f32, row t+4 clamped), C -> vhT fp16 [b][h][dk][SPAD]
//         (epilogue transposes 128x64 tile through LDS -> coalesced stores)
// MODE 1: A = xatt (fp16), C -> d_out f32, rows t<2044 only
// Tile 128x64, 4 waves, BK=32, mfma_f32_16x16x32_f16.
// ---------------------------------------------------------------------------
template <int MODE>
__global__ __launch_bounds__(256) void k_gemm(
    const void* __restrict__ Aptr, const f16_t* __restrict__ WT,
    const float* __restrict__ bias, void* __restrict__ Cptr) {
    __shared__ alignas(16) char smem[MODE == 0 ? 17408 : 15360];
    f16_t (*Asm)[40] = (f16_t(*)[40])smem;                 // [128][40]
    f16_t (*Bsm)[40] = (f16_t(*)[40])(smem + 128 * 40 * 2); // [64][40]
    const int tid = threadIdx.x, lane = tid & 63, wid = tid >> 6;
    const int mt = blockIdx.x >> 3, nt = blockIdx.x & 7;
    const int m0 = mt * 128, n0 = nt * 64;
    const int l15 = lane & 15, lg = lane >> 4;
    f32x4 acc[2][4] = {};

    for (int k0 = 0; k0 < 512; k0 += 32) {
        if (MODE == 0) {
            const float* A = (const float*)Aptr;
            int r = tid >> 1, cb = (tid & 1) * 16;
            int rp = m0 + r, b = rp >> 11, t = rp & 2047;
            int vrow = t + 4; vrow = vrow < 2047 ? vrow : 2047;
            const float4* src = (const float4*)(A + ((size_t)b * 2048 + vrow) * 512 + k0 + cb);
            float4 f0 = src[0], f1 = src[1], f2 = src[2], f3 = src[3];
            f16x8 p0, p1;
            p0[0] = (f16_t)f0.x; p0[1] = (f16_t)f0.y; p0[2] = (f16_t)f0.z; p0[3] = (f16_t)f0.w;
            p0[4] = (f16_t)f1.x; p0[5] = (f16_t)f1.y; p0[6] = (f16_t)f1.z; p0[7] = (f16_t)f1.w;
            p1[0] = (f16_t)f2.x; p1[1] = (f16_t)f2.y; p1[2] = (f16_t)f2.z; p1[3] = (f16_t)f2.w;
            p1[4] = (f16_t)f3.x; p1[5] = (f16_t)f3.y; p1[6] = (f16_t)f3.z; p1[7] = (f16_t)f3.w;
            *(f16x8*)&Asm[r][cb] = p0;
            *(f16x8*)&Asm[r][cb + 8] = p1;
        } else {
            const f16_t* A = (const f16_t*)Aptr;
#pragma unroll
            for (int i = 0; i < 2; i++) {
                int ch = tid + 256 * i, r = ch >> 2, off = (ch & 3) * 8;
                *(uint4*)&Asm[r][off] = *(const uint4*)(A + (size_t)(m0 + r) * 512 + k0 + off);
            }
        }
        {
            int nl = tid >> 2, koff = (tid & 3) * 8;
            *(uint4*)&Bsm[nl][koff] = *(const uint4*)(WT + (size_t)(n0 + nl) * 512 + k0 + koff);
        }
        __syncthreads();
        f16x8 af[2], bfr[4];
#pragma unroll
        for (int i = 0; i < 2; i++) af[i] = *(const f16x8*)&Asm[wid * 32 + i * 16 + l15][lg * 8];
#pragma unroll
        for (int c = 0; c < 4; c++) bfr[c] = *(const f16x8*)&Bsm[c * 16 + l15][lg * 8];
#pragma unroll
        for (int i = 0; i < 2; i++) {
#pragma unroll
            for (int c = 0; c < 4; c++) acc[i][c] = mfma16(af[i], bfr[c], acc[i][c]);
        }
        __syncthreads();
    }

    if (MODE == 0) {
        // Transpose 128(m) x 64(n) tile through LDS -> vhT[b][h][dk][SPAD]
        f16_t (*Csm)[136] = (f16_t(*)[136])smem;           // [64 dk][136 m]
#pragma unroll
        for (int i = 0; i < 2; i++) {
#pragma unroll
            for (int c = 0; c < 4; c++) {
                int col = n0 + c * 16 + l15;
                float bv = bias[col];
                f16x4 pk;
#pragma unroll
                for (int r = 0; r < 4; r++) pk[r] = (f16_t)(acc[i][c][r] + bv);
                *(f16x4*)&Csm[c * 16 + l15][wid * 32 + i * 16 + lg * 4] = pk;
            }
        }
        __syncthreads();
        const int b = m0 >> 11, t0 = m0 & 2047, h = n0 >> 6;
        const int dk = tid >> 2, mo = (tid & 3) * 32;
        f16_t* dst = (f16_t*)Cptr + ((size_t)(b * H_ + h) * DK_ + dk) * SPAD_ + t0 + mo;
#pragma unroll
        for (int j = 0; j < 4; j++)
            *(uint4*)(dst + j * 8) = *(const uint4*)&Csm[dk][mo + j * 8];
    } else {
#pragma unroll
        for (int i = 0; i < 2; i++) {
#pragma unroll
            for (int c = 0; c < 4; c++) {
#pragma unroll
                for (int r = 0; r < 4; r++) {
                    int row = m0 + wid * 32 + i * 16 + lg * 4 + r;
                    int col = n0 + c * 16 + l15;
                    float v = acc[i][c][r] + bias[col];
                    int b = row >> 11, t = row & 2047;
                    if (t < SP_) {
                        float* outp = (float*)Cptr;
                        outp[((size_t)b * SP_ + t) * 512 + col] = v;
                    }
                }
            }
        }
    }
}

// ---------------------------------------------------------------------------
// Kernel 4: flash attention, swapped-operand form.
// Block = 4 waves, 64 Q-rows (16/wave), one (b,h). K tiles row-major, V tiles
// already transposed in global (vhT). S^T = mfma(K,Q): each lane owns ONE
// q-row (l15) and 16 k-slots -> softmax is lane-local + 2 shuffles.
// P packed to per-wave LDS [q][k] via b64 writes; PV: O^T = mfma(V^T, P^T).
// ---------------------------------------------------------------------------
__global__ __launch_bounds__(256) void k_attn(
    const f16_t* __restrict__ qh, const f16_t* __restrict__ kh,
    const f16_t* __restrict__ vhT, f16_t* __restrict__ xatt) {
    __shared__ alignas(16) f16_t Ksm[64][72];        // [s][d]
    __shared__ alignas(16) f16_t Vsm[64][72];        // [d][s]  (from vhT)
    __shared__ alignas(16) f16_t Plds[4][16][72];    // per-wave P[q][k]; reused as O^T->O
    const int tid = threadIdx.x, lane = tid & 63, wid = tid >> 6;
    const int bh = blockIdx.x >> 5, qt = blockIdx.x & 31;
    const f16_t* Q = qh + (size_t)bh * SPAD_ * DK_;
    const f16_t* K = kh + (size_t)bh * SPAD_ * DK_;
    const f16_t* VT = vhT + (size_t)bh * DK_ * SPAD_;
    const int l15 = lane & 15, lg = lane >> 4;
    const int qrow = qt * 64 + wid * 16;

    f16x8 qf[2];
#pragma unroll
    for (int kf = 0; kf < 2; kf++)
        qf[kf] = *(const f16x8*)(Q + (size_t)(qrow + l15) * DK_ + kf * 32 + lg * 8);

    f32x4 acc[4] = {};
    float mrun = -1e30f, lrun = 0.f;

    for (int s0 = 0; s0 < SPAD_; s0 += 64) {
        // stage K [s][d] and V^T [d][s] with pure vector loads
#pragma unroll
        for (int i = 0; i < 2; i++) {
            int ch = tid + 256 * i, r = ch >> 3, off = (ch & 7) * 8;
            *(uint4*)&Ksm[r][off] = *(const uint4*)(K + (size_t)(s0 + r) * DK_ + off);
            *(uint4*)&Vsm[r][off] = *(const uint4*)(VT + (size_t)r * SPAD_ + s0 + off);
        }
        __syncthreads();

        // S^T = K Q^T : lane holds S[k = s0+n*16+lg*4+r][q = qrow+l15]
        f32x4 Sv[4];
#pragma unroll
        for (int n = 0; n < 4; n++) {
            f16x8 kb0 = *(const f16x8*)&Ksm[n * 16 + l15][lg * 8];
            f16x8 kb1 = *(const f16x8*)&Ksm[n * 16 + l15][32 + lg * 8];
            f32x4 s = {};
            s = mfma16(kb0, qf[0], s);
            s = mfma16(kb1, qf[1], s);
            Sv[n] = s;
        }
        if (s0 + 64 > SP_) {
#pragma unroll
            for (int n = 0; n < 4; n++) {
                int kb = s0 + n * 16 + lg * 4;
#pragma unroll
                for (int r = 0; r < 4; r++)
                    if (kb + r >= SP_) Sv[n][r] = -1e30f;
            }
        }
        // online softmax, exp2 domain; per-lane row stats
        float tm = Sv[0][0];
#pragma unroll
        for (int n = 0; n < 4; n++) {
#pragma unroll
            for (int r = 0; r < 4; r++) tm = fmaxf(tm, Sv[n][r]);
        }
        tm = fmaxf(tm, __shfl_xor(tm, 16, 64));
        tm = fmaxf(tm, __shfl_xor(tm, 32, 64));
        float nm = fmaxf(mrun, tm);
        float alpha = __builtin_amdgcn_exp2f(mrun - nm);
        mrun = nm;
        float rs = 0.f;
#pragma unroll
        for (int n = 0; n < 4; n++) {
#pragma unroll
            for (int r = 0; r < 4; r++) {
                float p = __builtin_amdgcn_exp2f(Sv[n][r] - nm);
                Sv[n][r] = p;
                rs += p;
            }
        }
        rs += __shfl_xor(rs, 16, 64);
        rs += __shfl_xor(rs, 32, 64);
        lrun = lrun * alpha + rs;
#pragma unroll
        for (int c = 0; c < 4; c++) {
#pragma unroll
            for (int r = 0; r < 4; r++) acc[c][r] *= alpha;
        }
        // pack P -> per-wave LDS [q=l15][k], 4x ds_write_b64
#pragma unroll
        for (int n = 0; n < 4; n++) {
            f16x4 pk;
#pragma unroll
            for (int r = 0; r < 4; r++) pk[r] = (f16_t)Sv[n][r];
            *(f16x4*)&Plds[wid][l15][n * 16 + lg * 4] = pk;
        }
        // PV: O^T[d][q] += V^T[d][k] * P^T[k][q]
#pragma unroll
        for (int ko = 0; ko < 2; ko++) {
            f16x8 pa = *(const f16x8*)&Plds[wid][l15][ko * 32 + lg * 8];
#pragma unroll
            for (int c = 0; c < 4; c++) {
                f16x8 vb = *(const f16x8*)&Vsm[c * 16 + l15][ko * 32 + lg * 8];
                acc[c] = mfma16(vb, pa, acc[c]);
            }
        }
        __syncthreads();
    }

    // epilogue: O^T -> per-wave LDS [q][d] -> coalesced store of O rows
    float inv = 1.f / lrun;
#pragma unroll
    for (int c = 0; c < 4; c++) {
        f16x4 pk;
#pragma unroll
        for (int r = 0; r < 4; r++) pk[r] = (f16_t)(acc[c][r] * inv);
        *(f16x4*)&Plds[wid][l15][c * 16 + lg * 4] = pk;
    }
    const int b = bh >> 3, h = bh & 7;
    const int qr = lane >> 2, dc = (lane & 3) * 16;
    f16_t* dst = xatt + ((size_t)b * SPAD_ + qrow + qr) * D_ + h * DK_ + dc;
    *(uint4*)dst = *(const uint4*)&Plds[wid][qr][dc];
    *(uint4*)(dst + 8) = *(const uint4*)&Plds[wid][qr][dc + 8];
}

// ---------------------------------------------------------------------------
extern "C" void kernel_launch(void* const* d_in, const int* in_sizes, int n_in,
                              void* d_out, int out_size, void* d_ws, size_t ws_size,
                              hipStream_t stream) {
    const float* query = (const float*)d_in[0];
    const float* key   = (const float*)d_in[1];
    const float* value = (const float*)d_in[2];
    const float* W0    = (const float*)d_in[3];
    const float* b0    = (const float*)d_in[4];
    const float* Wout  = (const float*)d_in[5];
    const float* bout  = (const float*)d_in[6];
    float* out = (float*)d_out;

    char* w = (char*)d_ws;
    const size_t SZ = (size_t)B_ * H_ * SPAD_ * DK_ * sizeof(f16_t);  // 16 MB
    f16_t* qh   = (f16_t*)w; w += SZ;
    f16_t* kh   = (f16_t*)w; w += SZ;
    f16_t* vhT  = (f16_t*)w; w += SZ;
    f16_t* xatt = (f16_t*)w; w += SZ;
    f16_t* WT0  = (f16_t*)w; w += (size_t)512 * 512 * sizeof(f16_t);
    f16_t* WT1  = (f16_t*)w; w += (size_t)512 * 512 * sizeof(f16_t);

    k_convert_w<<<2048, 256, 0, stream>>>(W0, Wout, WT0, WT1);
    k_prep<<<4096, 256, 0, stream>>>(query, key, qh, kh);
    k_gemm<0><<<1024, 256, 0, stream>>>((const void*)value, WT0, b0, (void*)vhT);
    k_attn<<<2048, 256, 0, stream>>>(qh, kh, vhT, xatt);
    k_gemm<1><<<1024, 256, 0, stream>>>((const void*)xatt, WT1, bout, (void*)out);
}

// Round 4
// 182.092 us; speedup vs baseline: 2.2592x; 1.3441x over previous
//
#include <hip/hip_runtime.h>
#include <hip/hip_bf16.h>
#include <hip/hip_fp16.h>

#define B_ 8
#define S_ 2048
#define D_ 512
#define H_ 8
#define L_ 5
#define DK_ 64
#define SP_ 2044
#define SPAD_ 2048

typedef _Float16 f16_t;
typedef _Float16 f16x4 __attribute__((ext_vector_type(4)));
typedef _Float16 f16x8 __attribute__((ext_vector_type(8)));
typedef float f32x4 __attribute__((ext_vector_type(4)));

static __device__ __forceinline__ f32x4 mfma16(f16x8 a, f16x8 b, f32x4 c) {
    return __builtin_amdgcn_mfma_f32_16x16x32_f16(a, b, c, 0, 0, 0);
}

// ---------------------------------------------------------------------------
// Kernel 1: W0/Wout f32 -> fp16, stored TRANSPOSED: WT[n*512+k] = W[k*512+n]
// ---------------------------------------------------------------------------
__global__ __launch_bounds__(256) void k_convert_w(
    const float* __restrict__ W0, const float* __restrict__ Wout,
    f16_t* __restrict__ WT0, f16_t* __restrict__ WT1) {
    int idx = blockIdx.x * 256 + threadIdx.x;          // 0 .. 2*512*512-1
    int which = idx >> 18;
    int e = idx & 0x3FFFF;
    int k = e >> 9, n = e & 511;
    const float* W = which ? Wout : W0;
    f16_t* WT = which ? WT1 : WT0;
    WT[n * 512 + k] = (f16_t)W[k * 512 + n];
}

// ---------------------------------------------------------------------------
// Kernel 2: q/k local aggregation. One wave per (b,t). f32 math, fp16 store
// into head layout [B][H][SPAD][DK]. q pre-scaled by log2(e)/sqrt(DK).
// ---------------------------------------------------------------------------
__global__ __launch_bounds__(256) void k_prep(
    const float* __restrict__ Qin, const float* __restrict__ Kin,
    f16_t* __restrict__ qh, f16_t* __restrict__ kh) {
    const int lane = threadIdx.x & 63;
    const int wid = threadIdx.x >> 6;
    const int gw = blockIdx.x * 4 + wid;               // 0..16383
    const int b = gw >> 11;
    const int t = gw & 2047;
    const float* qb = Qin + (size_t)b * S_ * D_;
    const float* kb = Kin + (size_t)b * S_ * D_;
    const int d0 = lane * 8;

    float qs[8];
    float kl[5][8];
#pragma unroll
    for (int e = 0; e < 8; e++) qs[e] = 0.f;
#pragma unroll
    for (int l = 0; l < L_; l++) {
        int row = t + l; row = row < 2047 ? row : 2047;   // clamp (only pads)
        const float4* qp = (const float4*)(qb + (size_t)row * D_ + d0);
        float4 a = qp[0], c = qp[1];
        qs[0] += a.x; qs[1] += a.y; qs[2] += a.z; qs[3] += a.w;
        qs[4] += c.x; qs[5] += c.y; qs[6] += c.z; qs[7] += c.w;
        const float4* kp = (const float4*)(kb + (size_t)row * D_ + d0);
        float4 ka = kp[0], kc = kp[1];
        kl[l][0] = ka.x; kl[l][1] = ka.y; kl[l][2] = ka.z; kl[l][3] = ka.w;
        kl[l][4] = kc.x; kl[l][5] = kc.y; kl[l][6] = kc.z; kl[l][7] = kc.w;
    }
    float dot[5];
#pragma unroll
    for (int l = 0; l < 5; l++) {
        float d = 0.f;
#pragma unroll
        for (int e = 0; e < 8; e++) d += kl[4][e] * kl[l][e];
        dot[l] = d;
    }
#pragma unroll
    for (int m = 32; m; m >>= 1) {
#pragma unroll
        for (int l = 0; l < 5; l++) dot[l] += __shfl_xor(dot[l], m, 64);
    }
    const float sc = 0.044194173824159216f;            // 1/sqrt(512)
    float mx = dot[0];
#pragma unroll
    for (int l = 1; l < 5; l++) mx = fmaxf(mx, dot[l]);
    float w[5], sum = 0.f;
#pragma unroll
    for (int l = 0; l < 5; l++) { w[l] = __expf((dot[l] - mx) * sc); sum += w[l]; }
    float inv = 1.f / sum;
    float ks[8];
#pragma unroll
    for (int e = 0; e < 8; e++) {
        float v = 0.f;
#pragma unroll
        for (int l = 0; l < 5; l++) v += w[l] * kl[l][e];
        ks[e] = v * inv;
    }
    const int h = d0 >> 6, dk = d0 & 63;
    const size_t ob = ((size_t)(b * H_ + h) * SPAD_ + t) * DK_ + dk;
    const float qscale = 0.125f * 1.4426950408889634f;   // 1/sqrt(DK) * log2(e)
    f16x8 qpk, kpk;
#pragma unroll
    for (int e = 0; e < 8; e++) {
        qpk[e] = (f16_t)(qs[e] * qscale);
        kpk[e] = (f16_t)ks[e];
    }
    *(f16x8*)(qh + ob) = qpk;
    *(f16x8*)(kh + ob) = kpk;
}

// ---------------------------------------------------------------------------
// Kernel 3: GEMM  C[16384][512] = A[16384][512] * W[512][512] + bias
// MODE 0: A = value (f32, row t+4 clamped), C -> vhT fp16 [b][h][dk][SPAD]
// MODE 1: A = xatt (fp16), C -> d_out f32, rows t<2044 only
// Tile 128x128, 4 waves, BK=32, mfma_f32_16x16x32_f16.
// ---------------------------------------------------------------------------
template <int MODE>
__global__ __launch_bounds__(256) void k_gemm(
    const void* __restrict__ Aptr, const f16_t* __restrict__ WT,
    const float* __restrict__ bias, void* __restrict__ Cptr) {
    __shared__ alignas(16) char smem[MODE == 0 ? 34816 : 20480];
    f16_t (*Asm)[40] = (f16_t(*)[40])smem;                  // [128][40]
    f16_t (*Bsm)[40] = (f16_t(*)[40])(smem + 10240);        // [128][40]
    const int tid = threadIdx.x, lane = tid & 63, wid = tid >> 6;
    const int mt = blockIdx.x >> 2, nt = blockIdx.x & 3;
    const int m0 = mt * 128, n0 = nt * 128;
    const int l15 = lane & 15, lg = lane >> 4;
    f32x4 acc[2][8] = {};

    for (int k0 = 0; k0 < 512; k0 += 32) {
        if (MODE == 0) {
            const float* A = (const float*)Aptr;
            int r = tid >> 1, cb = (tid & 1) * 16;
            int rp = m0 + r, b = rp >> 11, t = rp & 2047;
            int vrow = t + 4; vrow = vrow < 2047 ? vrow : 2047;
            const float4* src = (const float4*)(A + ((size_t)b * 2048 + vrow) * 512 + k0 + cb);
            float4 f0 = src[0], f1 = src[1], f2 = src[2], f3 = src[3];
            f16x8 p0, p1;
            p0[0] = (f16_t)f0.x; p0[1] = (f16_t)f0.y; p0[2] = (f16_t)f0.z; p0[3] = (f16_t)f0.w;
            p0[4] = (f16_t)f1.x; p0[5] = (f16_t)f1.y; p0[6] = (f16_t)f1.z; p0[7] = (f16_t)f1.w;
            p1[0] = (f16_t)f2.x; p1[1] = (f16_t)f2.y; p1[2] = (f16_t)f2.z; p1[3] = (f16_t)f2.w;
            p1[4] = (f16_t)f3.x; p1[5] = (f16_t)f3.y; p1[6] = (f16_t)f3.z; p1[7] = (f16_t)f3.w;
            *(f16x8*)&Asm[r][cb] = p0;
            *(f16x8*)&Asm[r][cb + 8] = p1;
        } else {
            const f16_t* A = (const f16_t*)Aptr;
#pragma unroll
            for (int i = 0; i < 2; i++) {
                int ch = tid + 256 * i, r = ch >> 2, off = (ch & 3) * 8;
                *(uint4*)&Asm[r][off] = *(const uint4*)(A + (size_t)(m0 + r) * 512 + k0 + off);
            }
        }
#pragma unroll
        for (int i = 0; i < 2; i++) {
            int ch = tid + 256 * i, nl = ch >> 2, koff = (ch & 3) * 8;
            *(uint4*)&Bsm[nl][koff] = *(const uint4*)(WT + (size_t)(n0 + nl) * 512 + k0 + koff);
        }
        __syncthreads();
        f16x8 af[2], bfr[8];
#pragma unroll
        for (int i = 0; i < 2; i++) af[i] = *(const f16x8*)&Asm[wid * 32 + i * 16 + l15][lg * 8];
#pragma unroll
        for (int c = 0; c < 8; c++) bfr[c] = *(const f16x8*)&Bsm[c * 16 + l15][lg * 8];
        __builtin_amdgcn_s_setprio(1);
#pragma unroll
        for (int i = 0; i < 2; i++) {
#pragma unroll
            for (int c = 0; c < 8; c++) acc[i][c] = mfma16(af[i], bfr[c], acc[i][c]);
        }
        __builtin_amdgcn_s_setprio(0);
        __syncthreads();
    }

    if (MODE == 0) {
        // Transpose 128(m) x 128(n) tile through LDS -> vhT[b][h][dk][SPAD]
        f16_t (*Csm)[136] = (f16_t(*)[136])smem;            // [128 col][136 m]
#pragma unroll
        for (int i = 0; i < 2; i++) {
#pragma unroll
            for (int c = 0; c < 8; c++) {
                int col = n0 + c * 16 + l15;
                float bv = bias[col];
                f16x4 pk;
#pragma unroll
                for (int r = 0; r < 4; r++) pk[r] = (f16_t)(acc[i][c][r] + bv);
                *(f16x4*)&Csm[c * 16 + l15][wid * 32 + i * 16 + lg * 4] = pk;
            }
        }
        __syncthreads();
        const int b = m0 >> 11, t0 = m0 & 2047;
        const int cl = tid >> 1, mo = (tid & 1) * 64;
        const int h = (n0 + cl) >> 6, dk = (n0 + cl) & 63;
        f16_t* dst = (f16_t*)Cptr + ((size_t)(b * H_ + h) * DK_ + dk) * SPAD_ + t0 + mo;
#pragma unroll
        for (int j = 0; j < 8; j++)                         // 8x16B = 64 m (BUGFIX: was 4)
            *(uint4*)(dst + j * 8) = *(const uint4*)&Csm[cl][mo + j * 8];
    } else {
#pragma unroll
        for (int i = 0; i < 2; i++) {
#pragma unroll
            for (int c = 0; c < 8; c++) {
#pragma unroll
                for (int r = 0; r < 4; r++) {
                    int row = m0 + wid * 32 + i * 16 + lg * 4 + r;
                    int col = n0 + c * 16 + l15;
                    float v = acc[i][c][r] + bias[col];
                    int b = row >> 11, t = row & 2047;
                    if (t < SP_) {
                        float* outp = (float*)Cptr;
                        outp[((size_t)b * SP_ + t) * 512 + col] = v;
                    }
                }
            }
        }
    }
}

// ---------------------------------------------------------------------------
// Kernel 4: flash attention, swapped-operand + STATIC-MAX softmax.
// Block = 4 waves, 128 Q-rows (32/wave in 2 halves), one (b,h) per 16 blocks.
// QK accumulator initialized to -12 (static softmax bias, folded into MFMA C).
// P = exp2(S-12) directly (shift-invariant); row-sum via mfma(ones, P, rsacc).
// No per-tile max, no rescale, no shuffles.
// ---------------------------------------------------------------------------
__global__ __launch_bounds__(256) void k_attn(
    const f16_t* __restrict__ qh, const f16_t* __restrict__ kh,
    const f16_t* __restrict__ vhT, f16_t* __restrict__ xatt) {
    __shared__ alignas(16) f16_t Ksm[64][72];         // [s][d]
    __shared__ alignas(16) f16_t Vsm[64][72];         // [d][s]  (from vhT)
    __shared__ alignas(16) f16_t Plds[4][2][16][72];  // per-wave, per-half P[q][k]
    const int tid = threadIdx.x, lane = tid & 63, wid = tid >> 6;
    const int bh = blockIdx.x >> 4, qt = blockIdx.x & 15;
    const f16_t* Q = qh + (size_t)bh * SPAD_ * DK_;
    const f16_t* K = kh + (size_t)bh * SPAD_ * DK_;
    const f16_t* VT = vhT + (size_t)bh * DK_ * SPAD_;
    const int l15 = lane & 15, lg = lane >> 4;
    const int qbase = qt * 128 + wid * 32;

    f16x8 qf[2][2];
#pragma unroll
    for (int h = 0; h < 2; h++)
#pragma unroll
        for (int kf = 0; kf < 2; kf++)
            qf[h][kf] = *(const f16x8*)(Q + (size_t)(qbase + h * 16 + l15) * DK_ + kf * 32 + lg * 8);

    f16x8 ones;
#pragma unroll
    for (int e = 0; e < 8; e++) ones[e] = (f16_t)1.0f;
    const f32x4 cinit = {-12.f, -12.f, -12.f, -12.f};

    f32x4 acc[2][4] = {};
    f32x4 rsacc[2] = {};

    // hoisted staging addresses
    const int sr = tid >> 3, soff = (tid & 7) * 8;          // rows 0..31 / 32..63
    const f16_t* kp0 = K + (size_t)sr * DK_ + soff;
    const f16_t* kp1 = K + (size_t)(sr + 32) * DK_ + soff;
    const f16_t* vp0 = VT + (size_t)sr * SPAD_ + soff;
    const f16_t* vp1 = VT + (size_t)(sr + 32) * SPAD_ + soff;

    for (int s0 = 0; s0 < SPAD_; s0 += 64) {
        *(uint4*)&Ksm[sr][soff]      = *(const uint4*)(kp0 + (size_t)s0 * DK_);
        *(uint4*)&Ksm[sr + 32][soff] = *(const uint4*)(kp1 + (size_t)s0 * DK_);
        *(uint4*)&Vsm[sr][soff]      = *(const uint4*)(vp0 + s0);
        *(uint4*)&Vsm[sr + 32][soff] = *(const uint4*)(vp1 + s0);
        __syncthreads();

        // S^T = K Q^T + (-12): lane holds S[k = s0+n*16+lg*4+r][q]
        f32x4 Sv[2][4];
        __builtin_amdgcn_s_setprio(1);
#pragma unroll
        for (int n = 0; n < 4; n++) {
            f16x8 kb0 = *(const f16x8*)&Ksm[n * 16 + l15][lg * 8];
            f16x8 kb1 = *(const f16x8*)&Ksm[n * 16 + l15][32 + lg * 8];
#pragma unroll
            for (int h = 0; h < 2; h++) {
                f32x4 s = mfma16(kb0, qf[h][0], cinit);
                s = mfma16(kb1, qf[h][1], s);
                Sv[h][n] = s;
            }
        }
        __builtin_amdgcn_s_setprio(0);
        if (s0 + 64 > SP_) {
#pragma unroll
            for (int n = 0; n < 4; n++) {
                int kb = s0 + n * 16 + lg * 4;
#pragma unroll
                for (int r = 0; r < 4; r++)
                    if (kb + r >= SP_) { Sv[0][n][r] = -1e30f; Sv[1][n][r] = -1e30f; }
            }
        }
        // P = exp2(S) -> f16 -> per-wave LDS [q][k]
#pragma unroll
        for (int h = 0; h < 2; h++) {
#pragma unroll
            for (int n = 0; n < 4; n++) {
                f16x4 pk;
#pragma unroll
                for (int r = 0; r < 4; r++)
                    pk[r] = (f16_t)__builtin_amdgcn_exp2f(Sv[h][n][r]);
                *(f16x4*)&Plds[wid][h][l15][n * 16 + lg * 4] = pk;
            }
        }
        // PV: O^T += V^T P^T ; row-sum via ones-MFMA
        __builtin_amdgcn_s_setprio(1);
#pragma unroll
        for (int ko = 0; ko < 2; ko++) {
            f16x8 pa0 = *(const f16x8*)&Plds[wid][0][l15][ko * 32 + lg * 8];
            f16x8 pa1 = *(const f16x8*)&Plds[wid][1][l15][ko * 32 + lg * 8];
            rsacc[0] = mfma16(ones, pa0, rsacc[0]);
            rsacc[1] = mfma16(ones, pa1, rsacc[1]);
#pragma unroll
            for (int c = 0; c < 4; c++) {
                f16x8 vb = *(const f16x8*)&Vsm[c * 16 + l15][ko * 32 + lg * 8];
                acc[0][c] = mfma16(vb, pa0, acc[0][c]);
                acc[1][c] = mfma16(vb, pa1, acc[1][c]);
            }
        }
        __builtin_amdgcn_s_setprio(0);
        __syncthreads();
    }

    // epilogue: O^T -> per-wave LDS [q][d] -> coalesced store of O rows
    const int b = bh >> 3, hh = bh & 7;
#pragma unroll
    for (int h = 0; h < 2; h++) {
        float inv = 1.f / rsacc[h][0];
#pragma unroll
        for (int c = 0; c < 4; c++) {
            f16x4 pk;
#pragma unroll
            for (int r = 0; r < 4; r++) pk[r] = (f16_t)(acc[h][c][r] * inv);
            *(f16x4*)&Plds[wid][h][l15][c * 16 + lg * 4] = pk;
        }
    }
    const int qr = lane >> 2, dc = (lane & 3) * 16;
#pragma unroll
    for (int h = 0; h < 2; h++) {
        f16_t* dst = xatt + ((size_t)b * SPAD_ + qbase + h * 16 + qr) * D_ + hh * DK_ + dc;
        *(uint4*)dst = *(const uint4*)&Plds[wid][h][qr][dc];
        *(uint4*)(dst + 8) = *(const uint4*)&Plds[wid][h][qr][dc + 8];
    }
}

// ---------------------------------------------------------------------------
extern "C" void kernel_launch(void* const* d_in, const int* in_sizes, int n_in,
                              void* d_out, int out_size, void* d_ws, size_t ws_size,
                              hipStream_t stream) {
    const float* query = (const float*)d_in[0];
    const float* key   = (const float*)d_in[1];
    const float* value = (const float*)d_in[2];
    const float* W0    = (const float*)d_in[3];
    const float* b0    = (const float*)d_in[4];
    const float* Wout  = (const float*)d_in[5];
    const float* bout  = (const float*)d_in[6];
    float* out = (float*)d_out;

    char* w = (char*)d_ws;
    const size_t SZ = (size_t)B_ * H_ * SPAD_ * DK_ * sizeof(f16_t);  // 16 MB
    f16_t* qh   = (f16_t*)w; w += SZ;
    f16_t* kh   = (f16_t*)w; w += SZ;
    f16_t* vhT  = (f16_t*)w; w += SZ;
    f16_t* xatt = (f16_t*)w; w += SZ;
    f16_t* WT0  = (f16_t*)w; w += (size_t)512 * 512 * sizeof(f16_t);
    f16_t* WT1  = (f16_t*)w; w += (size_t)512 * 512 * sizeof(f16_t);

    k_convert_w<<<2048, 256, 0, stream>>>(W0, Wout, WT0, WT1);
    k_prep<<<4096, 256, 0, stream>>>(query, key, qh, kh);
    k_gemm<0><<<512, 256, 0, stream>>>((const void*)value, WT0, b0, (void*)vhT);
    k_attn<<<1024, 256, 0, stream>>>(qh, kh, vhT, xatt);
    k_gemm<1><<<512, 256, 0, stream>>>((const void*)xatt, WT1, bout, (void*)out);
}

// Round 6
// 178.771 us; speedup vs baseline: 2.3012x; 1.0186x over previous
//
#include <hip/hip_runtime.h>
#include <hip/hip_bf16.h>
#include <hip/hip_fp16.h>

#define B_ 8
#define S_ 2048
#define D_ 512
#define H_ 8
#define L_ 5
#define DK_ 64
#define SP_ 2044
#define SPAD_ 2048

typedef _Float16 f16_t;
typedef _Float16 f16x4 __attribute__((ext_vector_type(4)));
typedef _Float16 f16x8 __attribute__((ext_vector_type(8)));
typedef __fp16 fp16x2_b __attribute__((ext_vector_type(2)));   // builtin cvt_pkrtz type
typedef float f32x4 __attribute__((ext_vector_type(4)));

static __device__ __forceinline__ f32x4 mfma16(f16x8 a, f16x8 b, f32x4 c) {
    return __builtin_amdgcn_mfma_f32_16x16x32_f16(a, b, c, 0, 0, 0);
}

union PK4 { f16x4 v; fp16x2_b h[2]; };

// ---------------------------------------------------------------------------
// Kernel 1: W0/Wout f32 -> fp16, stored TRANSPOSED: WT[n*512+k] = W[k*512+n]
// ---------------------------------------------------------------------------
__global__ __launch_bounds__(256) void k_convert_w(
    const float* __restrict__ W0, const float* __restrict__ Wout,
    f16_t* __restrict__ WT0, f16_t* __restrict__ WT1) {
    int idx = blockIdx.x * 256 + threadIdx.x;          // 0 .. 2*512*512-1
    int which = idx >> 18;
    int e = idx & 0x3FFFF;
    int k = e >> 9, n = e & 511;
    const float* W = which ? Wout : W0;
    f16_t* WT = which ? WT1 : WT0;
    WT[n * 512 + k] = (f16_t)W[k * 512 + n];
}

// ---------------------------------------------------------------------------
// Kernel 2: q/k local aggregation. One wave per (b,t). f32 math, fp16 store
// into head layout [B][H][SPAD][DK]. q pre-scaled by log2(e)/sqrt(DK).
// ---------------------------------------------------------------------------
__global__ __launch_bounds__(256) void k_prep(
    const float* __restrict__ Qin, const float* __restrict__ Kin,
    f16_t* __restrict__ qh, f16_t* __restrict__ kh) {
    const int lane = threadIdx.x & 63;
    const int wid = threadIdx.x >> 6;
    const int gw = blockIdx.x * 4 + wid;               // 0..16383
    const int b = gw >> 11;
    const int t = gw & 2047;
    const float* qb = Qin + (size_t)b * S_ * D_;
    const float* kb = Kin + (size_t)b * S_ * D_;
    const int d0 = lane * 8;

    float qs[8];
    float kl[5][8];
#pragma unroll
    for (int e = 0; e < 8; e++) qs[e] = 0.f;
#pragma unroll
    for (int l = 0; l < L_; l++) {
        int row = t + l; row = row < 2047 ? row : 2047;   // clamp (only pads)
        const float4* qp = (const float4*)(qb + (size_t)row * D_ + d0);
        float4 a = qp[0], c = qp[1];
        qs[0] += a.x; qs[1] += a.y; qs[2] += a.z; qs[3] += a.w;
        qs[4] += c.x; qs[5] += c.y; qs[6] += c.z; qs[7] += c.w;
        const float4* kp = (const float4*)(kb + (size_t)row * D_ + d0);
        float4 ka = kp[0], kc = kp[1];
        kl[l][0] = ka.x; kl[l][1] = ka.y; kl[l][2] = ka.z; kl[l][3] = ka.w;
        kl[l][4] = kc.x; kl[l][5] = kc.y; kl[l][6] = kc.z; kl[l][7] = kc.w;
    }
    float dot[5];
#pragma unroll
    for (int l = 0; l < 5; l++) {
        float d = 0.f;
#pragma unroll
        for (int e = 0; e < 8; e++) d += kl[4][e] * kl[l][e];
        dot[l] = d;
    }
#pragma unroll
    for (int m = 32; m; m >>= 1) {
#pragma unroll
        for (int l = 0; l < 5; l++) dot[l] += __shfl_xor(dot[l], m, 64);
    }
    const float sc = 0.044194173824159216f;            // 1/sqrt(512)
    float mx = dot[0];
#pragma unroll
    for (int l = 1; l < 5; l++) mx = fmaxf(mx, dot[l]);
    float w[5], sum = 0.f;
#pragma unroll
    for (int l = 0; l < 5; l++) { w[l] = __expf((dot[l] - mx) * sc); sum += w[l]; }
    float inv = 1.f / sum;
    float ks[8];
#pragma unroll
    for (int e = 0; e < 8; e++) {
        float v = 0.f;
#pragma unroll
        for (int l = 0; l < 5; l++) v += w[l] * kl[l][e];
        ks[e] = v * inv;
    }
    const int h = d0 >> 6, dk = d0 & 63;
    const size_t ob = ((size_t)(b * H_ + h) * SPAD_ + t) * DK_ + dk;
    const float qscale = 0.125f * 1.4426950408889634f;   // 1/sqrt(DK) * log2(e)
    f16x8 qpk, kpk;
#pragma unroll
    for (int e = 0; e < 8; e++) {
        qpk[e] = (f16_t)(qs[e] * qscale);
        kpk[e] = (f16_t)ks[e];
    }
    *(f16x8*)(qh + ob) = qpk;
    *(f16x8*)(kh + ob) = kpk;
}

// ---------------------------------------------------------------------------
// Kernel 3: GEMM  C[16384][512] = A[16384][512] * W[512][512] + bias
// MODE 0: A = value (f32, row t+4 clamped), C -> vhT fp16 [b][h][dk][SPAD]
// MODE 1: A = xatt (fp16), C -> d_out f32, rows t<2044 only
// Tile 128x128, 4 waves, BK=32. Double-buffered LDS, reg-staged loads,
// ONE barrier per K-step (T14 async-stage pattern).
// ---------------------------------------------------------------------------
template <int MODE>
__global__ __launch_bounds__(256) void k_gemm(
    const void* __restrict__ Aptr, const f16_t* __restrict__ WT,
    const float* __restrict__ bias, void* __restrict__ Cptr) {
    __shared__ alignas(16) char smem[40960];
    // A0 [0,10240) A1 [10240,20480) B0 [20480,30720) B1 [30720,40960)
    const int tid = threadIdx.x, lane = tid & 63, wid = tid >> 6;
    const int mt = blockIdx.x >> 2, nt = blockIdx.x & 3;
    const int m0 = mt * 128, n0 = nt * 128;
    const int l15 = lane & 15, lg = lane >> 4;
    f32x4 acc[2][8] = {};

    // staging source pointers (k0 added per step)
    const float* a0src = nullptr;       // MODE 0
    const f16_t* a1src0 = nullptr, *a1src1 = nullptr;  // MODE 1 (2 chunks)
    if (MODE == 0) {
        const float* A = (const float*)Aptr;
        int r = tid >> 1, cb = (tid & 1) * 16;
        int rp = m0 + r, b = rp >> 11, t = rp & 2047;
        int vrow = t + 4; vrow = vrow < 2047 ? vrow : 2047;
        a0src = A + ((size_t)b * 2048 + vrow) * 512 + cb;
    } else {
        const f16_t* A = (const f16_t*)Aptr;
        int r0 = tid >> 2, off0 = (tid & 3) * 8;
        int r1 = (tid + 256) >> 2, off1 = (tid & 3) * 8;
        a1src0 = A + (size_t)(m0 + r0) * 512 + off0;
        a1src1 = A + (size_t)(m0 + r1) * 512 + off1;
    }
    const int bnl0 = tid >> 2, bko0 = (tid & 3) * 8;
    const int bnl1 = (tid + 256) >> 2;
    const f16_t* bsrc0 = WT + (size_t)(n0 + bnl0) * 512 + bko0;
    const f16_t* bsrc1 = WT + (size_t)(n0 + bnl1) * 512 + bko0;

    // register staging
    float4 fa[4];
    uint4 ua0, ua1, ub0, ub1;
    if (MODE == 0) {
#pragma unroll
        for (int j = 0; j < 4; j++) fa[j] = *(const float4*)(a0src + j * 4);
    } else {
        ua0 = *(const uint4*)a1src0;
        ua1 = *(const uint4*)a1src1;
    }
    ub0 = *(const uint4*)bsrc0;
    ub1 = *(const uint4*)bsrc1;

    for (int kt = 0; kt < 16; ++kt) {
        const int cur = kt & 1;
        f16_t (*Asm)[40] = (f16_t(*)[40])(smem + cur * 10240);
        f16_t (*Bsm)[40] = (f16_t(*)[40])(smem + 20480 + cur * 10240);
        // ds_write staged regs
        if (MODE == 0) {
            int r = tid >> 1, cb = (tid & 1) * 16;
            f16x8 p0, p1;
            p0[0] = (f16_t)fa[0].x; p0[1] = (f16_t)fa[0].y; p0[2] = (f16_t)fa[0].z; p0[3] = (f16_t)fa[0].w;
            p0[4] = (f16_t)fa[1].x; p0[5] = (f16_t)fa[1].y; p0[6] = (f16_t)fa[1].z; p0[7] = (f16_t)fa[1].w;
            p1[0] = (f16_t)fa[2].x; p1[1] = (f16_t)fa[2].y; p1[2] = (f16_t)fa[2].z; p1[3] = (f16_t)fa[2].w;
            p1[4] = (f16_t)fa[3].x; p1[5] = (f16_t)fa[3].y; p1[6] = (f16_t)fa[3].z; p1[7] = (f16_t)fa[3].w;
            *(f16x8*)&Asm[r][cb] = p0;
            *(f16x8*)&Asm[r][cb + 8] = p1;
        } else {
            int r0 = tid >> 2, r1 = (tid + 256) >> 2, off = (tid & 3) * 8;
            *(uint4*)&Asm[r0][off] = ua0;
            *(uint4*)&Asm[r1][off] = ua1;
        }
        *(uint4*)&Bsm[bnl0][bko0] = ub0;
        *(uint4*)&Bsm[bnl1][bko0] = ub1;
        // issue next-step loads (fly across compute)
        if (kt < 15) {
            const int k0n = (kt + 1) * 32;
            if (MODE == 0) {
#pragma unroll
                for (int j = 0; j < 4; j++) fa[j] = *(const float4*)(a0src + k0n + j * 4);
            } else {
                ua0 = *(const uint4*)(a1src0 + k0n);
                ua1 = *(const uint4*)(a1src1 + k0n);
            }
            ub0 = *(const uint4*)(bsrc0 + k0n);
            ub1 = *(const uint4*)(bsrc1 + k0n);
        }
        __syncthreads();
        f16x8 af[2], bfr[8];
#pragma unroll
        for (int i = 0; i < 2; i++) af[i] = *(const f16x8*)&Asm[wid * 32 + i * 16 + l15][lg * 8];
#pragma unroll
        for (int c = 0; c < 8; c++) bfr[c] = *(const f16x8*)&Bsm[c * 16 + l15][lg * 8];
        __builtin_amdgcn_s_setprio(1);
#pragma unroll
        for (int i = 0; i < 2; i++) {
#pragma unroll
            for (int c = 0; c < 8; c++) acc[i][c] = mfma16(af[i], bfr[c], acc[i][c]);
        }
        __builtin_amdgcn_s_setprio(0);
        // single barrier per step: buf[cur] overwritten only 2 steps later,
        // which is provably after all waves' compute on it (barrier ordering)
    }

    if (MODE == 0) {
        __syncthreads();    // all waves done computing before Csm overlays smem
        // Transpose 128(m) x 128(n) tile through LDS -> vhT[b][h][dk][SPAD]
        f16_t (*Csm)[136] = (f16_t(*)[136])smem;            // [128 col][136 m]
#pragma unroll
        for (int i = 0; i < 2; i++) {
#pragma unroll
            for (int c = 0; c < 8; c++) {
                int col = n0 + c * 16 + l15;
                float bv = bias[col];
                f16x4 pk;
#pragma unroll
                for (int r = 0; r < 4; r++) pk[r] = (f16_t)(acc[i][c][r] + bv);
                *(f16x4*)&Csm[c * 16 + l15][wid * 32 + i * 16 + lg * 4] = pk;
            }
        }
        __syncthreads();
        const int b = m0 >> 11, t0 = m0 & 2047;
        const int cl = tid >> 1, mo = (tid & 1) * 64;
        const int h = (n0 + cl) >> 6, dk = (n0 + cl) & 63;
        f16_t* dst = (f16_t*)Cptr + ((size_t)(b * H_ + h) * DK_ + dk) * SPAD_ + t0 + mo;
#pragma unroll
        for (int j = 0; j < 8; j++)
            *(uint4*)(dst + j * 8) = *(const uint4*)&Csm[cl][mo + j * 8];
    } else {
#pragma unroll
        for (int i = 0; i < 2; i++) {
#pragma unroll
            for (int c = 0; c < 8; c++) {
#pragma unroll
                for (int r = 0; r < 4; r++) {
                    int row = m0 + wid * 32 + i * 16 + lg * 4 + r;
                    int col = n0 + c * 16 + l15;
                    float v = acc[i][c][r] + bias[col];
                    int b = row >> 11, t = row & 2047;
                    if (t < SP_) {
                        float* outp = (float*)Cptr;
                        outp[((size_t)b * SP_ + t) * 512 + col] = v;
                    }
                }
            }
        }
    }
}

// ---------------------------------------------------------------------------
// Kernel 4: flash attention, swapped-operand + static-max softmax.
// LDS double-buffer + reg-staged K/V + ONE barrier per tile (T14);
// XCD-chunked block swizzle (16 q-tiles of one bh on one XCD -> K/V L2-hot);
// cvt_pkrtz packed f32->f16 for P.
// ---------------------------------------------------------------------------
__global__ __launch_bounds__(256) void k_attn(
    const f16_t* __restrict__ qh, const f16_t* __restrict__ kh,
    const f16_t* __restrict__ vhT, f16_t* __restrict__ xatt) {
    __shared__ alignas(16) f16_t Ksm[2][64][68];      // [buf][s][d]
    __shared__ alignas(16) f16_t Vsm[2][64][68];      // [buf][d][s]
    __shared__ alignas(16) f16_t Plds[4][2][16][68];  // per-wave, per-half P[q][k]
    const int tid = threadIdx.x, lane = tid & 63, wid = tid >> 6;
    const int vb = ((blockIdx.x & 7) << 7) | (blockIdx.x >> 3);  // XCD-chunked (1024%8==0)
    const int bh = vb >> 4, qt = vb & 15;
    const f16_t* Q = qh + (size_t)bh * SPAD_ * DK_;
    const f16_t* K = kh + (size_t)bh * SPAD_ * DK_;
    const f16_t* VT = vhT + (size_t)bh * DK_ * SPAD_;
    const int l15 = lane & 15, lg = lane >> 4;
    const int qbase = qt * 128 + wid * 32;

    f16x8 qf[2][2];
#pragma unroll
    for (int h = 0; h < 2; h++)
#pragma unroll
        for (int kf = 0; kf < 2; kf++)
            qf[h][kf] = *(const f16x8*)(Q + (size_t)(qbase + h * 16 + l15) * DK_ + kf * 32 + lg * 8);

    f16x8 ones;
#pragma unroll
    for (int e = 0; e < 8; e++) ones[e] = (f16_t)1.0f;
    const f32x4 cinit = {-12.f, -12.f, -12.f, -12.f};

    f32x4 acc[2][4] = {};
    f32x4 rsacc[2] = {};

    // staging: each thread owns 16B of rows sr and sr+32 for K and V^T
    const int sr = tid >> 3, so = (tid & 7) * 8;
    const f16_t* kg0 = K + (size_t)sr * DK_ + so;
    const f16_t* kg1 = K + (size_t)(sr + 32) * DK_ + so;
    const f16_t* vg0 = VT + (size_t)sr * SPAD_ + so;
    const f16_t* vg1 = VT + (size_t)(sr + 32) * SPAD_ + so;

    uint4 rk0 = *(const uint4*)kg0;
    uint4 rk1 = *(const uint4*)kg1;
    uint4 rv0 = *(const uint4*)vg0;
    uint4 rv1 = *(const uint4*)vg1;

    for (int t = 0; t < 32; ++t) {
        const int cur = t & 1;
        *(uint4*)&Ksm[cur][sr][so]      = rk0;
        *(uint4*)&Ksm[cur][sr + 32][so] = rk1;
        *(uint4*)&Vsm[cur][sr][so]      = rv0;
        *(uint4*)&Vsm[cur][sr + 32][so] = rv1;
        if (t < 31) {
            const int nxt = (t + 1) << 6;
            rk0 = *(const uint4*)(kg0 + (size_t)nxt * DK_);
            rk1 = *(const uint4*)(kg1 + (size_t)nxt * DK_);
            rv0 = *(const uint4*)(vg0 + nxt);
            rv1 = *(const uint4*)(vg1 + nxt);
        }
        __syncthreads();   // single barrier per tile (dbuf makes WAR safe)

        // S^T = K Q^T + (-12): lane holds S[k = t*64+n*16+lg*4+r][q]
        f32x4 Sv[2][4];
        __builtin_amdgcn_s_setprio(1);
#pragma unroll
        for (int n = 0; n < 4; n++) {
            f16x8 kb0 = *(const f16x8*)&Ksm[cur][n * 16 + l15][lg * 8];
            f16x8 kb1 = *(const f16x8*)&Ksm[cur][n * 16 + l15][32 + lg * 8];
#pragma unroll
            for (int h = 0; h < 2; h++) {
                f32x4 s = mfma16(kb0, qf[h][0], cinit);
                s = mfma16(kb1, qf[h][1], s);
                Sv[h][n] = s;
            }
        }
        __builtin_amdgcn_s_setprio(0);
        if (t == 31) {
#pragma unroll
            for (int n = 0; n < 4; n++) {
                int kb = 1984 + n * 16 + lg * 4;
#pragma unroll
                for (int r = 0; r < 4; r++)
                    if (kb + r >= SP_) { Sv[0][n][r] = -1e30f; Sv[1][n][r] = -1e30f; }
            }
        }
        // P = exp2(S) -> f16 (packed cvt) -> per-wave LDS [q][k]
#pragma unroll
        for (int h = 0; h < 2; h++) {
#pragma unroll
            for (int n = 0; n < 4; n++) {
                float e0 = __builtin_amdgcn_exp2f(Sv[h][n][0]);
                float e1 = __builtin_amdgcn_exp2f(Sv[h][n][1]);
                float e2 = __builtin_amdgcn_exp2f(Sv[h][n][2]);
                float e3 = __builtin_amdgcn_exp2f(Sv[h][n][3]);
                PK4 pk;
                pk.h[0] = __builtin_amdgcn_cvt_pkrtz(e0, e1);
                pk.h[1] = __builtin_amdgcn_cvt_pkrtz(e2, e3);
                *(f16x4*)&Plds[wid][h][l15][n * 16 + lg * 4] = pk.v;
            }
        }
        // PV: O^T += V^T P^T ; row-sum via ones-MFMA
        __builtin_amdgcn_s_setprio(1);
#pragma unroll
        for (int ko = 0; ko < 2; ko++) {
            f16x8 pa0 = *(const f16x8*)&Plds[wid][0][l15][ko * 32 + lg * 8];
            f16x8 pa1 = *(const f16x8*)&Plds[wid][1][l15][ko * 32 + lg * 8];
            rsacc[0] = mfma16(ones, pa0, rsacc[0]);
            rsacc[1] = mfma16(ones, pa1, rsacc[1]);
#pragma unroll
            for (int c = 0; c < 4; c++) {
                f16x8 vb2 = *(const f16x8*)&Vsm[cur][c * 16 + l15][ko * 32 + lg * 8];
                acc[0][c] = mfma16(vb2, pa0, acc[0][c]);
                acc[1][c] = mfma16(vb2, pa1, acc[1][c]);
            }
        }
        __builtin_amdgcn_s_setprio(0);
    }

    // epilogue: O^T -> per-wave LDS [q][d] -> coalesced store of O rows
    // (Plds regions are per-wave; no barrier needed)
    const int b = bh >> 3, hh = bh & 7;
#pragma unroll
    for (int h = 0; h < 2; h++) {
        float inv = 1.f / rsacc[h][0];
#pragma unroll
        for (int c = 0; c < 4; c++) {
            f16x4 pk;
#pragma unroll
            for (int r = 0; r < 4; r++) pk[r] = (f16_t)(acc[h][c][r] * inv);
            *(f16x4*)&Plds[wid][h][l15][c * 16 + lg * 4] = pk;
        }
    }
    const int qr = lane >> 2, dc = (lane & 3) * 16;
#pragma unroll
    for (int h = 0; h < 2; h++) {
        f16_t* dst = xatt + ((size_t)b * SPAD_ + qbase + h * 16 + qr) * D_ + hh * DK_ + dc;
        *(uint4*)dst = *(const uint4*)&Plds[wid][h][qr][dc];
        *(uint4*)(dst + 8) = *(const uint4*)&Plds[wid][h][qr][dc + 8];
    }
}

// ---------------------------------------------------------------------------
extern "C" void kernel_launch(void* const* d_in, const int* in_sizes, int n_in,
                              void* d_out, int out_size, void* d_ws, size_t ws_size,
                              hipStream_t stream) {
    const float* query = (const float*)d_in[0];
    const float* key   = (const float*)d_in[1];
    const float* value = (const float*)d_in[2];
    const float* W0    = (const float*)d_in[3];
    const float* b0    = (const float*)d_in[4];
    const float* Wout  = (const float*)d_in[5];
    const float* bout  = (const float*)d_in[6];
    float* out = (float*)d_out;

    char* w = (char*)d_ws;
    const size_t SZ = (size_t)B_ * H_ * SPAD_ * DK_ * sizeof(f16_t);  // 16 MB
    f16_t* qh   = (f16_t*)w; w += SZ;
    f16_t* kh   = (f16_t*)w; w += SZ;
    f16_t* vhT  = (f16_t*)w; w += SZ;
    f16_t* xatt = (f16_t*)w; w += SZ;
    f16_t* WT0  = (f16_t*)w; w += (size_t)512 * 512 * sizeof(f16_t);
    f16_t* WT1  = (f16_t*)w; w += (size_t)512 * 512 * sizeof(f16_t);

    k_convert_w<<<2048, 256, 0, stream>>>(W0, Wout, WT0, WT1);
    k_prep<<<4096, 256, 0, stream>>>(query, key, qh, kh);
    k_gemm<0><<<512, 256, 0, stream>>>((const void*)value, WT0, b0, (void*)vhT);
    k_attn<<<1024, 256, 0, stream>>>(qh, kh, vhT, xatt);
    k_gemm<1><<<512, 256, 0, stream>>>((const void*)xatt, WT1, bout, (void*)out);
}

// Round 7
// 154.201 us; speedup vs baseline: 2.6679x; 1.1593x over previous
//
#include <hip/hip_runtime.h>
#include <hip/hip_bf16.h>
#include <hip/hip_fp16.h>

#define B_ 8
#define S_ 2048
#define D_ 512
#define H_ 8
#define L_ 5
#define DK_ 64
#define SP_ 2044
#define SPAD_ 2048

typedef _Float16 f16_t;
typedef _Float16 f16x4 __attribute__((ext_vector_type(4)));
typedef _Float16 f16x8 __attribute__((ext_vector_type(8)));
typedef __fp16 fp16x2_b __attribute__((ext_vector_type(2)));   // builtin half2 type
typedef float f32x4 __attribute__((ext_vector_type(4)));
typedef float f32x16 __attribute__((ext_vector_type(16)));
typedef unsigned int u32;

static __device__ __forceinline__ f32x4 mfma16(f16x8 a, f16x8 b, f32x4 c) {
    return __builtin_amdgcn_mfma_f32_16x16x32_f16(a, b, c, 0, 0, 0);
}
static __device__ __forceinline__ f32x16 mfma32(f16x8 a, f16x8 b, f32x16 c) {
    return __builtin_amdgcn_mfma_f32_32x32x16_f16(a, b, c, 0, 0, 0);
}

union PK4 { f16x4 v; fp16x2_b h[2]; };
union U32H2 { u32 u; fp16x2_b h; };
union FRAG { uint4 u; f16x8 f; };

// (r0, r1) = ({a.lo, b.lo}, {a.hi, b.hi}) across the lane<32 / lane>=32 split
static __device__ __forceinline__ void swap32(u32 a, u32 b, u32& r0, u32& r1, int hi) {
#if __has_builtin(__builtin_amdgcn_permlane32_swap)
    auto r = __builtin_amdgcn_permlane32_swap(a, b, false, false);
    r0 = r[0]; r1 = r[1];
#else
    u32 t = __shfl_xor(hi ? a : b, 32, 64);
    r0 = hi ? t : a;
    r1 = hi ? b : t;
#endif
}

// ---------------------------------------------------------------------------
// Kernel 1: W0/Wout f32 -> fp16, stored TRANSPOSED: WT[n*512+k] = W[k*512+n]
// ---------------------------------------------------------------------------
__global__ __launch_bounds__(256) void k_convert_w(
    const float* __restrict__ W0, const float* __restrict__ Wout,
    f16_t* __restrict__ WT0, f16_t* __restrict__ WT1) {
    int idx = blockIdx.x * 256 + threadIdx.x;          // 0 .. 2*512*512-1
    int which = idx >> 18;
    int e = idx & 0x3FFFF;
    int k = e >> 9, n = e & 511;
    const float* W = which ? Wout : W0;
    f16_t* WT = which ? WT1 : WT0;
    WT[n * 512 + k] = (f16_t)W[k * 512 + n];
}

// ---------------------------------------------------------------------------
// Kernel 2: q/k local aggregation. One wave per (b,t). f32 math, fp16 store
// into head layout [B][H][SPAD][DK]. q pre-scaled by log2(e)/sqrt(DK).
// ---------------------------------------------------------------------------
__global__ __launch_bounds__(256) void k_prep(
    const float* __restrict__ Qin, const float* __restrict__ Kin,
    f16_t* __restrict__ qh, f16_t* __restrict__ kh) {
    const int lane = threadIdx.x & 63;
    const int wid = threadIdx.x >> 6;
    const int gw = blockIdx.x * 4 + wid;               // 0..16383
    const int b = gw >> 11;
    const int t = gw & 2047;
    const float* qb = Qin + (size_t)b * S_ * D_;
    const float* kb = Kin + (size_t)b * S_ * D_;
    const int d0 = lane * 8;

    float qs[8];
    float kl[5][8];
#pragma unroll
    for (int e = 0; e < 8; e++) qs[e] = 0.f;
#pragma unroll
    for (int l = 0; l < L_; l++) {
        int row = t + l; row = row < 2047 ? row : 2047;   // clamp (only pads)
        const float4* qp = (const float4*)(qb + (size_t)row * D_ + d0);
        float4 a = qp[0], c = qp[1];
        qs[0] += a.x; qs[1] += a.y; qs[2] += a.z; qs[3] += a.w;
        qs[4] += c.x; qs[5] += c.y; qs[6] += c.z; qs[7] += c.w;
        const float4* kp = (const float4*)(kb + (size_t)row * D_ + d0);
        float4 ka = kp[0], kc = kp[1];
        kl[l][0] = ka.x; kl[l][1] = ka.y; kl[l][2] = ka.z; kl[l][3] = ka.w;
        kl[l][4] = kc.x; kl[l][5] = kc.y; kl[l][6] = kc.z; kl[l][7] = kc.w;
    }
    float dot[5];
#pragma unroll
    for (int l = 0; l < 5; l++) {
        float d = 0.f;
#pragma unroll
        for (int e = 0; e < 8; e++) d += kl[4][e] * kl[l][e];
        dot[l] = d;
    }
#pragma unroll
    for (int m = 32; m; m >>= 1) {
#pragma unroll
        for (int l = 0; l < 5; l++) dot[l] += __shfl_xor(dot[l], m, 64);
    }
    const float sc = 0.044194173824159216f;            // 1/sqrt(512)
    float mx = dot[0];
#pragma unroll
    for (int l = 1; l < 5; l++) mx = fmaxf(mx, dot[l]);
    float w[5], sum = 0.f;
#pragma unroll
    for (int l = 0; l < 5; l++) { w[l] = __expf((dot[l] - mx) * sc); sum += w[l]; }
    float inv = 1.f / sum;
    float ks[8];
#pragma unroll
    for (int e = 0; e < 8; e++) {
        float v = 0.f;
#pragma unroll
        for (int l = 0; l < 5; l++) v += w[l] * kl[l][e];
        ks[e] = v * inv;
    }
    const int h = d0 >> 6, dk = d0 & 63;
    const size_t ob = ((size_t)(b * H_ + h) * SPAD_ + t) * DK_ + dk;
    const float qscale = 0.125f * 1.4426950408889634f;   // 1/sqrt(DK) * log2(e)
    f16x8 qpk, kpk;
#pragma unroll
    for (int e = 0; e < 8; e++) {
        qpk[e] = (f16_t)(qs[e] * qscale);
        kpk[e] = (f16_t)ks[e];
    }
    *(f16x8*)(qh + ob) = qpk;
    *(f16x8*)(kh + ob) = kpk;
}

// ---------------------------------------------------------------------------
// Kernel 3: GEMM  C[16384][512] = A[16384][512] * W[512][512] + bias
// MODE 0: A = value (f32, row t+4 clamped), C -> vhT fp16 [b][h][dk][SPAD]
// MODE 1: A = xatt (fp16), C -> d_out f32, rows t<2044 only
// Tile 128x128, 4 waves, BK=32. Double-buffered LDS, reg-staged loads,
// ONE barrier per K-step.
// ---------------------------------------------------------------------------
template <int MODE>
__global__ __launch_bounds__(256) void k_gemm(
    const void* __restrict__ Aptr, const f16_t* __restrict__ WT,
    const float* __restrict__ bias, void* __restrict__ Cptr) {
    __shared__ alignas(16) char smem[40960];
    const int tid = threadIdx.x, lane = tid & 63, wid = tid >> 6;
    const int mt = blockIdx.x >> 2, nt = blockIdx.x & 3;
    const int m0 = mt * 128, n0 = nt * 128;
    const int l15 = lane & 15, lg = lane >> 4;
    f32x4 acc[2][8] = {};

    const float* a0src = nullptr;
    const f16_t* a1src0 = nullptr, *a1src1 = nullptr;
    if (MODE == 0) {
        const float* A = (const float*)Aptr;
        int r = tid >> 1, cb = (tid & 1) * 16;
        int rp = m0 + r, b = rp >> 11, t = rp & 2047;
        int vrow = t + 4; vrow = vrow < 2047 ? vrow : 2047;
        a0src = A + ((size_t)b * 2048 + vrow) * 512 + cb;
    } else {
        const f16_t* A = (const f16_t*)Aptr;
        int r0 = tid >> 2, off0 = (tid & 3) * 8;
        int r1 = (tid + 256) >> 2;
        a1src0 = A + (size_t)(m0 + r0) * 512 + off0;
        a1src1 = A + (size_t)(m0 + r1) * 512 + off0;
    }
    const int bnl0 = tid >> 2, bko0 = (tid & 3) * 8;
    const int bnl1 = (tid + 256) >> 2;
    const f16_t* bsrc0 = WT + (size_t)(n0 + bnl0) * 512 + bko0;
    const f16_t* bsrc1 = WT + (size_t)(n0 + bnl1) * 512 + bko0;

    float4 fa[4];
    uint4 ua0, ua1, ub0, ub1;
    if (MODE == 0) {
#pragma unroll
        for (int j = 0; j < 4; j++) fa[j] = *(const float4*)(a0src + j * 4);
    } else {
        ua0 = *(const uint4*)a1src0;
        ua1 = *(const uint4*)a1src1;
    }
    ub0 = *(const uint4*)bsrc0;
    ub1 = *(const uint4*)bsrc1;

    for (int kt = 0; kt < 16; ++kt) {
        const int cur = kt & 1;
        f16_t (*Asm)[40] = (f16_t(*)[40])(smem + cur * 10240);
        f16_t (*Bsm)[40] = (f16_t(*)[40])(smem + 20480 + cur * 10240);
        if (MODE == 0) {
            int r = tid >> 1, cb = (tid & 1) * 16;
            f16x8 p0, p1;
            p0[0] = (f16_t)fa[0].x; p0[1] = (f16_t)fa[0].y; p0[2] = (f16_t)fa[0].z; p0[3] = (f16_t)fa[0].w;
            p0[4] = (f16_t)fa[1].x; p0[5] = (f16_t)fa[1].y; p0[6] = (f16_t)fa[1].z; p0[7] = (f16_t)fa[1].w;
            p1[0] = (f16_t)fa[2].x; p1[1] = (f16_t)fa[2].y; p1[2] = (f16_t)fa[2].z; p1[3] = (f16_t)fa[2].w;
            p1[4] = (f16_t)fa[3].x; p1[5] = (f16_t)fa[3].y; p1[6] = (f16_t)fa[3].z; p1[7] = (f16_t)fa[3].w;
            *(f16x8*)&Asm[r][cb] = p0;
            *(f16x8*)&Asm[r][cb + 8] = p1;
        } else {
            int r0 = tid >> 2, r1 = (tid + 256) >> 2, off = (tid & 3) * 8;
            *(uint4*)&Asm[r0][off] = ua0;
            *(uint4*)&Asm[r1][off] = ua1;
        }
        *(uint4*)&Bsm[bnl0][bko0] = ub0;
        *(uint4*)&Bsm[bnl1][bko0] = ub1;
        if (kt < 15) {
            const int k0n = (kt + 1) * 32;
            if (MODE == 0) {
#pragma unroll
                for (int j = 0; j < 4; j++) fa[j] = *(const float4*)(a0src + k0n + j * 4);
            } else {
                ua0 = *(const uint4*)(a1src0 + k0n);
                ua1 = *(const uint4*)(a1src1 + k0n);
            }
            ub0 = *(const uint4*)(bsrc0 + k0n);
            ub1 = *(const uint4*)(bsrc1 + k0n);
        }
        __syncthreads();
        f16x8 af[2], bfr[8];
#pragma unroll
        for (int i = 0; i < 2; i++) af[i] = *(const f16x8*)&Asm[wid * 32 + i * 16 + l15][lg * 8];
#pragma unroll
        for (int c = 0; c < 8; c++) bfr[c] = *(const f16x8*)&Bsm[c * 16 + l15][lg * 8];
        __builtin_amdgcn_s_setprio(1);
#pragma unroll
        for (int i = 0; i < 2; i++) {
#pragma unroll
            for (int c = 0; c < 8; c++) acc[i][c] = mfma16(af[i], bfr[c], acc[i][c]);
        }
        __builtin_amdgcn_s_setprio(0);
    }

    if (MODE == 0) {
        __syncthreads();
        f16_t (*Csm)[136] = (f16_t(*)[136])smem;            // [128 col][136 m]
#pragma unroll
        for (int i = 0; i < 2; i++) {
#pragma unroll
            for (int c = 0; c < 8; c++) {
                int col = n0 + c * 16 + l15;
                float bv = bias[col];
                f16x4 pk;
#pragma unroll
                for (int r = 0; r < 4; r++) pk[r] = (f16_t)(acc[i][c][r] + bv);
                *(f16x4*)&Csm[c * 16 + l15][wid * 32 + i * 16 + lg * 4] = pk;
            }
        }
        __syncthreads();
        const int b = m0 >> 11, t0 = m0 & 2047;
        const int cl = tid >> 1, mo = (tid & 1) * 64;
        const int h = (n0 + cl) >> 6, dk = (n0 + cl) & 63;
        f16_t* dst = (f16_t*)Cptr + ((size_t)(b * H_ + h) * DK_ + dk) * SPAD_ + t0 + mo;
#pragma unroll
        for (int j = 0; j < 8; j++)
            *(uint4*)(dst + j * 8) = *(const uint4*)&Csm[cl][mo + j * 8];
    } else {
#pragma unroll
        for (int i = 0; i < 2; i++) {
#pragma unroll
            for (int c = 0; c < 8; c++) {
#pragma unroll
                for (int r = 0; r < 4; r++) {
                    int row = m0 + wid * 32 + i * 16 + lg * 4 + r;
                    int col = n0 + c * 16 + l15;
                    float v = acc[i][c][r] + bias[col];
                    int b = row >> 11, t = row & 2047;
                    if (t < SP_) {
                        float* outp = (float*)Cptr;
                        outp[((size_t)b * SP_ + t) * 512 + col] = v;
                    }
                }
            }
        }
    }
}

// ---------------------------------------------------------------------------
// Kernel 4: flash attention on mfma_f32_32x32x16_f16.
// Block = 4 waves x 64 q-rows = 256 q; grid 512 = exactly 2 blocks/CU.
// S^T = mfma32(K, Q) + (-12)  (static-max, exp2 domain).
// P stays in REGISTERS: cvt_pkrtz pairs + permlane32_swap map QK output regs
// directly onto the PV B-fragment. Row-sum via v_dot2 on packed P.
// K/V LDS double-buffered, reg-staged, one barrier per tile.
// ---------------------------------------------------------------------------
__global__ __launch_bounds__(256, 2) void k_attn(
    const f16_t* __restrict__ qh, const f16_t* __restrict__ kh,
    const f16_t* __restrict__ vhT, f16_t* __restrict__ xatt) {
    __shared__ alignas(16) f16_t Ksm[2][64][68];      // [buf][s][d]
    __shared__ alignas(16) f16_t Vsm[2][64][68];      // [buf][d][s]
    const int tid = threadIdx.x, lane = tid & 63, wid = tid >> 6;
    const int l31 = lane & 31, hi = lane >> 5, hi8 = hi * 8;
    const int vb = ((blockIdx.x & 7) << 6) | (blockIdx.x >> 3);  // XCD-chunked (512%8==0)
    const int bh = vb >> 3, qt = vb & 7;
    const f16_t* Q = qh + (size_t)bh * SPAD_ * DK_;
    const f16_t* K = kh + (size_t)bh * SPAD_ * DK_;
    const f16_t* VT = vhT + (size_t)bh * DK_ * SPAD_;
    const int qw = qt * 256 + wid * 64;               // wave's q base

    // Q fragments (B-operand): lane l31 owns q-col (qw + qg*32 + l31)
    f16x8 qf[2][4];
#pragma unroll
    for (int qg = 0; qg < 2; qg++)
#pragma unroll
        for (int kf = 0; kf < 4; kf++)
            qf[qg][kf] = *(const f16x8*)(Q + (size_t)(qw + qg * 32 + l31) * DK_ + kf * 16 + hi8);

    f32x16 cinit;
#pragma unroll
    for (int i = 0; i < 16; i++) cinit[i] = -12.f;

    f32x16 acc[2][2] = {};                 // [qg][dc] : O^T[d][q]
    float rsa[2] = {0.f, 0.f}, rsb[2] = {0.f, 0.f};
    u32 pk[2][2][8];                       // [qg][kr][j]
    U32H2 one2; one2.u = 0x3C003C00u;      // (1.0h, 1.0h)

    // staging: each thread owns 16B of rows sr and sr+32 for K and V^T
    const int sr = tid >> 3, so = (tid & 7) * 8;
    const f16_t* kg0 = K + (size_t)sr * DK_ + so;
    const f16_t* kg1 = K + (size_t)(sr + 32) * DK_ + so;
    const f16_t* vg0 = VT + (size_t)sr * SPAD_ + so;
    const f16_t* vg1 = VT + (size_t)(sr + 32) * SPAD_ + so;

    uint4 rk0 = *(const uint4*)kg0;
    uint4 rk1 = *(const uint4*)kg1;
    uint4 rv0 = *(const uint4*)vg0;
    uint4 rv1 = *(const uint4*)vg1;

    for (int t = 0; t < 32; ++t) {
        const int cur = t & 1;
        *(uint4*)&Ksm[cur][sr][so]      = rk0;
        *(uint4*)&Ksm[cur][sr + 32][so] = rk1;
        *(uint4*)&Vsm[cur][sr][so]      = rv0;
        *(uint4*)&Vsm[cur][sr + 32][so] = rv1;
        if (t < 31) {
            const int nxt = (t + 1) << 6;
            rk0 = *(const uint4*)(kg0 + (size_t)nxt * DK_);
            rk1 = *(const uint4*)(kg1 + (size_t)nxt * DK_);
            rv0 = *(const uint4*)(vg0 + nxt);
            rv1 = *(const uint4*)(vg1 + nxt);
        }
        __syncthreads();   // single barrier per tile (dbuf makes WAR safe)

        // ---- QK^T per kr-half: S^T[k][q], lane owns col q, 16 k-rows ----
#pragma unroll
        for (int kr = 0; kr < 2; ++kr) {
            f32x16 sv0 = cinit, sv1 = cinit;
            __builtin_amdgcn_s_setprio(1);
#pragma unroll
            for (int kf = 0; kf < 4; ++kf) {
                f16x8 a = *(const f16x8*)&Ksm[cur][kr * 32 + l31][kf * 16 + hi8];
                sv0 = mfma32(a, qf[0][kf], sv0);
                sv1 = mfma32(a, qf[1][kf], sv1);
            }
            __builtin_amdgcn_s_setprio(0);
            if (t == 31 && kr == 1) {      // mask k >= 2044 (rows 28..31 = hi regs 12..15)
#pragma unroll
                for (int r = 12; r < 16; ++r) {
                    sv0[r] = hi ? -1e30f : sv0[r];
                    sv1[r] = hi ? -1e30f : sv1[r];
                }
            }
            // P = exp2(S) -> packed f16 pairs; row-sum via dot2 on packed P
#pragma unroll
            for (int j = 0; j < 8; ++j) {
                float a0 = __builtin_amdgcn_exp2f(sv0[2 * j]);
                float a1 = __builtin_amdgcn_exp2f(sv0[2 * j + 1]);
                U32H2 c0; c0.h = __builtin_amdgcn_cvt_pkrtz(a0, a1);
                pk[0][kr][j] = c0.u;
                float b0 = __builtin_amdgcn_exp2f(sv1[2 * j]);
                float b1 = __builtin_amdgcn_exp2f(sv1[2 * j + 1]);
                U32H2 c1; c1.h = __builtin_amdgcn_cvt_pkrtz(b0, b1);
                pk[1][kr][j] = c1.u;
#if __has_builtin(__builtin_amdgcn_fdot2)
                if (j & 1) {
                    rsb[0] = __builtin_amdgcn_fdot2(c0.h, one2.h, rsb[0], false);
                    rsb[1] = __builtin_amdgcn_fdot2(c1.h, one2.h, rsb[1], false);
                } else {
                    rsa[0] = __builtin_amdgcn_fdot2(c0.h, one2.h, rsa[0], false);
                    rsa[1] = __builtin_amdgcn_fdot2(c1.h, one2.h, rsa[1], false);
                }
#else
                if (j & 1) { rsb[0] += a0 + a1; rsb[1] += b0 + b1; }
                else       { rsa[0] += a0 + a1; rsa[1] += b0 + b1; }
#endif
            }
        }

        // ---- PV: O^T[d][q] += V^T[d][kv] P^T[kv][q] ----
#pragma unroll
        for (int kc = 0; kc < 4; ++kc) {
            const int kr = kc >> 1, al = (kc & 1) * 4;
            FRAG p0, p1;
            {
                u32 m0, m1, m2, m3;
                swap32(pk[0][kr][al],     pk[0][kr][al + 2], m0, m2, hi);
                swap32(pk[0][kr][al + 1], pk[0][kr][al + 3], m1, m3, hi);
                p0.u = make_uint4(m0, m1, m2, m3);
                swap32(pk[1][kr][al],     pk[1][kr][al + 2], m0, m2, hi);
                swap32(pk[1][kr][al + 1], pk[1][kr][al + 3], m1, m3, hi);
                p1.u = make_uint4(m0, m1, m2, m3);
            }
            __builtin_amdgcn_s_setprio(1);
#pragma unroll
            for (int dc = 0; dc < 2; ++dc) {
                f16x8 v = *(const f16x8*)&Vsm[cur][dc * 32 + l31][kc * 16 + hi8];
                acc[0][dc] = mfma32(v, p0.f, acc[0][dc]);
                acc[1][dc] = mfma32(v, p1.f, acc[1][dc]);
            }
            __builtin_amdgcn_s_setprio(0);
        }
    }

    // ---- epilogue ----
    float rs0 = rsa[0] + rsb[0];
    float rs1 = rsa[1] + rsb[1];
    rs0 += __shfl_xor(rs0, 32, 64);        // combine hi halves (k-rows split)
    rs1 += __shfl_xor(rs1, 32, 64);
    const float inv[2] = {1.f / rs0, 1.f / rs1};

    __syncthreads();                       // all waves done with Ksm/Vsm
    f16_t (*Osm)[68] = (f16_t(*)[68])&Ksm[0][0][0];   // [256 q][68 d] overlay
#pragma unroll
    for (int qg = 0; qg < 2; ++qg) {
        const int row = wid * 64 + qg * 32 + l31;
#pragma unroll
        for (int dc = 0; dc < 2; ++dc) {
#pragma unroll
            for (int p = 0; p < 8; ++p) {
                float e0 = acc[qg][dc][2 * p] * inv[qg];
                float e1 = acc[qg][dc][2 * p + 1] * inv[qg];
                U32H2 c; c.h = __builtin_amdgcn_cvt_pkrtz(e0, e1);
                const int d = dc * 32 + 2 * (p & 1) + 8 * (p >> 1) + 4 * hi;
                *(u32*)&Osm[row][d] = c.u;
            }
        }
    }
    __syncthreads();
    const int b = bh >> 3, hh = bh & 7;
#pragma unroll
    for (int ps = 0; ps < 8; ++ps) {
        const int row = wid * 64 + ps * 8 + (lane >> 3);
        const int dco = (lane & 7) * 8;
        uint4 v = *(const uint4*)&Osm[row][dco];
        f16_t* dst = xatt + ((size_t)b * SPAD_ + qt * 256 + row) * D_ + hh * DK_ + dco;
        *(uint4*)dst = v;
    }
}

// ---------------------------------------------------------------------------
extern "C" void kernel_launch(void* const* d_in, const int* in_sizes, int n_in,
                              void* d_out, int out_size, void* d_ws, size_t ws_size,
                              hipStream_t stream) {
    const float* query = (const float*)d_in[0];
    const float* key   = (const float*)d_in[1];
    const float* value = (const float*)d_in[2];
    const float* W0    = (const float*)d_in[3];
    const float* b0    = (const float*)d_in[4];
    const float* Wout  = (const float*)d_in[5];
    const float* bout  = (const float*)d_in[6];
    float* out = (float*)d_out;

    char* w = (char*)d_ws;
    const size_t SZ = (size_t)B_ * H_ * SPAD_ * DK_ * sizeof(f16_t);  // 16 MB
    f16_t* qh   = (f16_t*)w; w += SZ;
    f16_t* kh   = (f16_t*)w; w += SZ;
    f16_t* vhT  = (f16_t*)w; w += SZ;
    f16_t* xatt = (f16_t*)w; w += SZ;
    f16_t* WT0  = (f16_t*)w; w += (size_t)512 * 512 * sizeof(f16_t);
    f16_t* WT1  = (f16_t*)w; w += (size_t)512 * 512 * sizeof(f16_t);

    k_convert_w<<<2048, 256, 0, stream>>>(W0, Wout, WT0, WT1);
    k_prep<<<4096, 256, 0, stream>>>(query, key, qh, kh);
    k_gemm<0><<<512, 256, 0, stream>>>((const void*)value, WT0, b0, (void*)vhT);
    k_attn<<<512, 256, 0, stream>>>(qh, kh, vhT, xatt);
    k_gemm<1><<<512, 256, 0, stream>>>((const void*)xatt, WT1, bout, (void*)out);
}